// Round 3
// baseline (591.081 us; speedup 1.0000x reference)
//
#include <hip/hip_runtime.h>
#include <hip/hip_bf16.h>
#include <math.h>

// Problem constants
#define Bz 2
#define Tz 512
#define Cz 2048
#define Hh 32
#define DH 64
#define NTOK (Bz * Tz)   // 1024
#define NCH 8            // chunks per sequence (Tz/64)

typedef __hip_bfloat16 bf16;
typedef __attribute__((ext_vector_type(8))) short short8;
typedef __attribute__((ext_vector_type(4))) float f32x4;

// ---------------------------------------------------------------------------
// async global->LDS, 16B per lane. LDS dest must be wave-uniform base;
// lanes land at base + lane*16.
__device__ __forceinline__ void load_lds16(const void* g, void* l) {
  __builtin_amdgcn_global_load_lds(
      (const __attribute__((address_space(1))) unsigned int*)g,
      (__attribute__((address_space(3))) unsigned int*)l,
      16, 0, 0);
}

// ---------------------------------------------------------------------------
// Weight transpose + f32->bf16: Wt[n][k] = (bf16) W[k][n].  z selects weight.
__global__ __launch_bounds__(256) void k_transpose(
    const float* __restrict__ qw, const float* __restrict__ kw,
    const float* __restrict__ vw, const float* __restrict__ ow,
    bf16* __restrict__ qwt, bf16* __restrict__ kwt,
    bf16* __restrict__ vwt, bf16* __restrict__ owt) {
  __shared__ float tile[32][33];
  const float* W;
  bf16* O;
  switch (blockIdx.z) {
    case 0: W = qw; O = qwt; break;
    case 1: W = kw; O = kwt; break;
    case 2: W = vw; O = vwt; break;
    default: W = ow; O = owt; break;
  }
  int bx = blockIdx.x * 32, by = blockIdx.y * 32;
  int tx = threadIdx.x, ty = threadIdx.y;
#pragma unroll
  for (int i = 0; i < 4; i++)
    tile[ty + 8 * i][tx] = W[(size_t)(by + ty + 8 * i) * Cz + bx + tx];
  __syncthreads();
#pragma unroll
  for (int i = 0; i < 4; i++)
    O[(size_t)(bx + ty + 8 * i) * Cz + by + tx] =
        __float2bfloat16(tile[tx][ty + 8 * i]);
}

// ---------------------------------------------------------------------------
// dx = x_{t-1} - x_t (zero pad at t=0);  xxx = x + dx*maa_x
__global__ __launch_bounds__(256) void k_prep(
    const float* __restrict__ x, const float* __restrict__ maa_x,
    float* __restrict__ dx, float* __restrict__ xxx) {
  int i4 = blockIdx.x * 256 + threadIdx.x;  // over 524288 float4
  int row = i4 >> 9;                        // 512 float4 per row
  int t = row & (Tz - 1);
  int c4 = i4 & 511;
  const float4* x4 = (const float4*)x;
  float4 xv = x4[i4];
  float4 xp = make_float4(0.f, 0.f, 0.f, 0.f);
  if (t != 0) xp = x4[i4 - 512];
  float4 mx = ((const float4*)maa_x)[c4];
  float4 d, xx;
  d.x = xp.x - xv.x; d.y = xp.y - xv.y; d.z = xp.z - xv.z; d.w = xp.w - xv.w;
  xx.x = xv.x + d.x * mx.x; xx.y = xv.y + d.y * mx.y;
  xx.z = xv.z + d.z * mx.z; xx.w = xv.w + d.w * mx.w;
  ((float4*)dx)[i4] = d;
  ((float4*)xxx)[i4] = xx;
}

// ---------------------------------------------------------------------------
// mm = tanh(xxx @ maa_w1)   [NTOK,128], 4 tokens per block, LDS-staged weights
__global__ __launch_bounds__(256) void k_mm(
    const float* __restrict__ xxx, const float* __restrict__ w1,
    float* __restrict__ mm) {
  __shared__ float sW[64][128];  // 32 KB weight K-chunk
  __shared__ float sX[4][64];
  int tid = threadIdx.x;
  int o = tid & 127, tg = tid >> 7;  // 2 token-groups of 2
  int tok0 = blockIdx.x * 4;
  float acc0 = 0.f, acc1 = 0.f;
  for (int kc = 0; kc < Cz; kc += 64) {
    {
      int t = tid >> 6, c = tid & 63;
      sX[t][c] = xxx[(size_t)(tok0 + t) * Cz + kc + c];
    }
#pragma unroll
    for (int u = 0; u < 8; u++) {
      int idx = tid + 256 * u;           // 2048 float4
      int row = idx >> 5, c4 = idx & 31;
      *(float4*)&sW[row][c4 * 4] =
          *(const float4*)&w1[(size_t)(kc + row) * 128 + c4 * 4];
    }
    __syncthreads();
#pragma unroll
    for (int c = 0; c < 64; c++) {
      float w = sW[c][o];
      acc0 += w * sX[tg * 2][c];
      acc1 += w * sX[tg * 2 + 1][c];
    }
    __syncthreads();
  }
  mm[(size_t)(tok0 + tg * 2) * 128 + o] = tanhf(acc0);
  mm[(size_t)(tok0 + tg * 2 + 1) * 128 + o] = tanhf(acc1);
}

// ---------------------------------------------------------------------------
// m_r = mm @ maa_w2[r]; fuse xr/xk/xv (bf16) and xw (f32) outputs.
// grid: (NTOK/8, Cz/256), block 256.
__global__ __launch_bounds__(256) void k_mproj(
    const float* __restrict__ mm, const float* __restrict__ w2,
    const float* __restrict__ x, const float* __restrict__ dx,
    const float* __restrict__ maa_r, const float* __restrict__ maa_k,
    const float* __restrict__ maa_v, const float* __restrict__ maa_w,
    bf16* __restrict__ pxr, bf16* __restrict__ pxk,
    bf16* __restrict__ pxv, float* __restrict__ pxw) {
  __shared__ float sM[8][128];
  int tid = threadIdx.x;
  int tok0 = blockIdx.x * 8;
  int c = blockIdx.y * 256 + tid;
#pragma unroll
  for (int u = 0; u < 4; u++) {
    int idx = tid + 256 * u;
    sM[idx >> 7][idx & 127] = mm[(size_t)tok0 * 128 + idx];
  }
  __syncthreads();
  float m_[4][8];
#pragma unroll
  for (int r = 0; r < 4; r++)
#pragma unroll
    for (int t = 0; t < 8; t++) m_[r][t] = 0.f;
#pragma unroll
  for (int r = 0; r < 4; r++) {
#pragma unroll 8
    for (int d = 0; d < 32; d++) {
      float w = w2[(size_t)(r * 32 + d) * Cz + c];
#pragma unroll
      for (int t = 0; t < 8; t++) m_[r][t] += w * sM[t][r * 32 + d];
    }
  }
  float mr = maa_r[c], mk = maa_k[c], mv = maa_v[c], mw = maa_w[c];
#pragma unroll
  for (int t = 0; t < 8; t++) {
    size_t idx = (size_t)(tok0 + t) * Cz + c;
    float xval = x[idx], dval = dx[idx];
    pxr[idx] = __float2bfloat16(xval + dval * (mr + m_[0][t]));
    pxk[idx] = __float2bfloat16(xval + dval * (mk + m_[1][t]));
    pxv[idx] = __float2bfloat16(xval + dval * (mv + m_[2][t]));
    pxw[idx] = xval + dval * (mw + m_[3][t]);
  }
}

// ---------------------------------------------------------------------------
// tw = tanh(xw @ td_w1)  [NTOK,64], 4 tokens per block, LDS-staged weights
__global__ __launch_bounds__(256) void k_tdA(
    const float* __restrict__ xw, const float* __restrict__ w1,
    float* __restrict__ tw) {
  __shared__ float sW[64][64];  // 16 KB weight K-chunk
  __shared__ float sX[4][64];
  int tid = threadIdx.x;
  int o = tid & 63, tg = tid >> 6;  // 4 tokens, 1 per group
  int tok0 = blockIdx.x * 4;
  float acc = 0.f;
  for (int kc = 0; kc < Cz; kc += 64) {
    {
      int t = tid >> 6, c = tid & 63;
      sX[t][c] = xw[(size_t)(tok0 + t) * Cz + kc + c];
    }
#pragma unroll
    for (int u = 0; u < 4; u++) {
      int idx = tid + 256 * u;           // 1024 float4
      int row = idx >> 4, c4 = idx & 15;
      *(float4*)&sW[row][c4 * 4] =
          *(const float4*)&w1[(size_t)(kc + row) * 64 + c4 * 4];
    }
    __syncthreads();
#pragma unroll
    for (int c = 0; c < 64; c++) acc += sW[c][o] * sX[tg][c];
    __syncthreads();
  }
  tw[(size_t)(tok0 + tg) * 64 + o] = tanhf(acc);
}

// ---------------------------------------------------------------------------
// w_log = max(-exp(td + tw @ td_w2), -5); write wlog (f32) and ksc = 1-exp(wlog)
// grid: (NTOK/8, Cz/256)
__global__ __launch_bounds__(256) void k_tdB(
    const float* __restrict__ tw, const float* __restrict__ w2,
    const float* __restrict__ td, float* __restrict__ wlog,
    float* __restrict__ ksc) {
  __shared__ float sT[8][64];
  int tid = threadIdx.x;
  int tok0 = blockIdx.x * 8;
  int c = blockIdx.y * 256 + tid;
#pragma unroll
  for (int u = 0; u < 2; u++) {
    int idx = tid + 256 * u;
    sT[idx >> 6][idx & 63] = tw[(size_t)tok0 * 64 + idx];
  }
  __syncthreads();
  float acc[8];
#pragma unroll
  for (int t = 0; t < 8; t++) acc[t] = 0.f;
#pragma unroll 8
  for (int d = 0; d < 64; d++) {
    float w = w2[(size_t)d * Cz + c];
#pragma unroll
    for (int t = 0; t < 8; t++) acc[t] += w * sT[t][d];
  }
  float tdc = td[c];
#pragma unroll
  for (int t = 0; t < 8; t++) {
    float wl = -expf(tdc + acc[t]);
    wl = fmaxf(wl, -5.0f);
    size_t idx = (size_t)(tok0 + t) * Cz + c;
    wlog[idx] = wl;
    ksc[idx] = 1.f - expf(wl);
  }
}

// ---------------------------------------------------------------------------
// m97-style bf16 MFMA GEMM: out[M=1024][N=2048] = A[M][K=2048] @ Wt[N][K]^T
__device__ __forceinline__ void gemm_tile(
    const bf16* __restrict__ A, const bf16* __restrict__ Wt,
    const float* __restrict__ bias, const float* __restrict__ kscale,
    float scl, float* __restrict__ out, int bM, int bN) {
  constexpr int K = Cz, N = Cz;
  __shared__ alignas(16) bf16 As[128 * 32];
  __shared__ alignas(16) bf16 Bs[128 * 32];
  int tid = threadIdx.x;
  int lane = tid & 63, wave = tid >> 6;
  int wm = wave & 1, wn = wave >> 1;

  f32x4 acc[4][4];
#pragma unroll
  for (int i = 0; i < 4; i++)
#pragma unroll
    for (int j = 0; j < 4; j++) acc[i][j] = (f32x4){0.f, 0.f, 0.f, 0.f};

  int srow = lane >> 2;
  int scol = (lane & 3) * 8;
  const bf16* gA = A + (size_t)(bM * 128 + wave * 16 + srow) * K + scol;
  const bf16* gB = Wt + (size_t)(bN * 128 + wave * 16 + srow) * K + scol;
  bf16* lA = As + (wave * 16) * 32;
  bf16* lB = Bs + (wave * 16) * 32;

  int fr = lane & 15, fk = (lane >> 4) * 8;
  const bf16* rA = As + (wm * 64 + fr) * 32 + fk;
  const bf16* rB = Bs + (wn * 64 + fr) * 32 + fk;

  for (int k0 = 0; k0 < K; k0 += 32) {
    load_lds16(gA + k0, lA);
    load_lds16(gA + (size_t)64 * K + k0, lA + 64 * 32);
    load_lds16(gB + k0, lB);
    load_lds16(gB + (size_t)64 * K + k0, lB + 64 * 32);
    __syncthreads();
    short8 af[4], bf[4];
#pragma unroll
    for (int i = 0; i < 4; i++) af[i] = *(const short8*)(rA + i * 16 * 32);
#pragma unroll
    for (int j = 0; j < 4; j++) bf[j] = *(const short8*)(rB + j * 16 * 32);
#pragma unroll
    for (int i = 0; i < 4; i++)
#pragma unroll
      for (int j = 0; j < 4; j++)
        acc[i][j] = __builtin_amdgcn_mfma_f32_16x16x32_bf16(af[i], bf[j],
                                                            acc[i][j], 0, 0, 0);
    __syncthreads();
  }

  int r0 = (lane >> 4) * 4;
  int cn = lane & 15;
#pragma unroll
  for (int i = 0; i < 4; i++) {
    int mbase = bM * 128 + wm * 64 + i * 16 + r0;
#pragma unroll
    for (int j = 0; j < 4; j++) {
      int n = bN * 128 + wn * 64 + j * 16 + cn;
      float bv = bias ? bias[n] : 0.f;
#pragma unroll
      for (int r = 0; r < 4; r++) {
        float vv = (acc[i][j][r] + bv) * scl;
        size_t oi = (size_t)(mbase + r) * N + n;
        if (kscale) vv *= kscale[oi];
        out[oi] = vv;
      }
    }
  }
}

__global__ __launch_bounds__(256) void k_gemm_qkv(
    const bf16* __restrict__ xr, const bf16* __restrict__ xk,
    const bf16* __restrict__ xv, const bf16* __restrict__ qwt,
    const bf16* __restrict__ kwt, const bf16* __restrict__ vwt,
    const float* __restrict__ qb, const float* __restrict__ kb,
    const float* __restrict__ vb, const float* __restrict__ kscl,
    float* __restrict__ q, float* __restrict__ k, float* __restrict__ v) {
  const bf16 *A, *W;
  const float* b;
  const float* ks = nullptr;
  float* o;
  float scl = 1.f;
  if (blockIdx.z == 0) {
    A = xr; W = qwt; b = qb; o = q; scl = 0.125f;  // fold Dh^-0.5 into q
  } else if (blockIdx.z == 1) {
    A = xk; W = kwt; b = kb; o = k; ks = kscl;
  } else {
    A = xv; W = vwt; b = vb; o = v;
  }
  gemm_tile(A, W, b, ks, scl, o, blockIdx.y, blockIdx.x);
}

__global__ __launch_bounds__(256) void k_gemm_o(
    const bf16* __restrict__ yb, const bf16* __restrict__ owt,
    float* __restrict__ out) {
  gemm_tile(yb, owt, nullptr, nullptr, 1.f, out, blockIdx.y, blockIdx.x);
}

// ---------------------------------------------------------------------------
// Chunked GLA pass 1: per (b,h,chunk of 64): cumsum of wlog; emit
// qt = q*exp(cum), kt = k*exp(-cum), kh = k*exp(cumL-cum) (bf16, chunk-major),
// aL[d] = exp(cumL), and U[d][j] = sum_s kh[s][d]*v[s][j].
__global__ __launch_bounds__(256) void k_chunk_prep(
    const float* __restrict__ q, const float* __restrict__ k,
    const float* __restrict__ v, const float* __restrict__ wlog,
    bf16* __restrict__ qt, bf16* __restrict__ kt, bf16* __restrict__ kh,
    float* __restrict__ aL, float* __restrict__ U) {
  __shared__ float sCum[64 * 64];
  __shared__ float sKh[64 * 64];
  __shared__ float sV[64 * 64];
  int tid = threadIdx.x;
  int bhc = blockIdx.x;
  int c = bhc & 7, h = (bhc >> 3) & 31, b = bhc >> 8;
  size_t gbase = ((size_t)(b * Tz) + c * 64) * Cz + h * 64;
  size_t cbase = (size_t)bhc * 4096;

  // load wlog, k, v (float4)
#pragma unroll
  for (int i = 0; i < 4; i++) {
    int i4 = tid + i * 256;           // 1024 float4
    int t = i4 >> 4, dq = i4 & 15;
    size_t g = gbase + (size_t)t * Cz + dq * 4;
    *(float4*)&sCum[t * 64 + dq * 4] = *(const float4*)&wlog[g];
    *(float4*)&sKh[t * 64 + dq * 4] = *(const float4*)&k[g];
    *(float4*)&sV[t * 64 + dq * 4] = *(const float4*)&v[g];
  }
  __syncthreads();
  // inclusive cumsum over t (lane d)
  if (tid < 64) {
    float cum = 0.f;
#pragma unroll
    for (int t = 0; t < 64; t++) {
      cum += sCum[t * 64 + tid];
      sCum[t * 64 + tid] = cum;
    }
  }
  __syncthreads();
  // scale & emit; overwrite sKh with K-hat (f32)
#pragma unroll
  for (int i = 0; i < 16; i++) {
    int idx = tid + i * 256;
    int t = idx >> 6, d = idx & 63;
    float cl = sCum[t * 64 + d];
    float cL = sCum[63 * 64 + d];
    float kraw = sKh[t * 64 + d];
    float qv = q[gbase + (size_t)t * Cz + d];
    float khv = kraw * expf(cL - cl);
    qt[cbase + idx] = __float2bfloat16(qv * expf(cl));
    kt[cbase + idx] = __float2bfloat16(kraw * expf(-cl));
    kh[cbase + idx] = __float2bfloat16(khv);
    sKh[t * 64 + d] = khv;
    if (t == 63) aL[(size_t)bhc * 64 + d] = expf(cl);
  }
  __syncthreads();
  // U[d][j] = sum_s Kh[s][d] * V[s][j]; thread (j=tid&63, dg=tid>>6)
  int j = tid & 63, dg = tid >> 6;
  float acc[16];
#pragma unroll
  for (int dd = 0; dd < 16; dd++) acc[dd] = 0.f;
  for (int s = 0; s < 64; s++) {
    float vs = sV[s * 64 + j];
#pragma unroll
    for (int dd = 0; dd < 16; dd++)
      acc[dd] += sKh[s * 64 + dg * 16 + dd] * vs;
  }
#pragma unroll
  for (int dd = 0; dd < 16; dd++)
    U[cbase + (size_t)(dg * 16 + dd) * 64 + j] = acc[dd];
}

// ---------------------------------------------------------------------------
// Chunked GLA pass 2 (sequential over 8 chunks): S_{c+1} = diag(aL)*S_c + U_c.
// Stores carry-in state per chunk. grid: 64 bh * 4 jg = 256 blocks, 64 thr.
__global__ __launch_bounds__(64) void k_carry(
    const float* __restrict__ aL, const float* __restrict__ U,
    float* __restrict__ Sc) {
  int bh = blockIdx.x >> 2;
  int jg = blockIdx.x & 3;
  int tid = threadIdx.x;
  int jj = tid & 15, dg = tid >> 4;
  int j = jg * 16 + jj;
  float S[16];
#pragma unroll
  for (int dd = 0; dd < 16; dd++) S[dd] = 0.f;
  for (int c = 0; c < NCH; c++) {
    int bhc = bh * NCH + c;
    size_t base = (size_t)bhc * 4096;
#pragma unroll
    for (int dd = 0; dd < 16; dd++) {
      int d = dg * 16 + dd;
      Sc[base + (size_t)d * 64 + j] = S[dd];
      S[dd] = S[dd] * aL[(size_t)bhc * 64 + d] + U[base + (size_t)d * 64 + j];
    }
  }
}

// ---------------------------------------------------------------------------
// Chunked GLA pass 3: o = mask(qt @ kt^T) @ V + qt @ S_c.  512 blocks.
__global__ __launch_bounds__(256) void k_chunk_out(
    const bf16* __restrict__ qt, const bf16* __restrict__ kt,
    const float* __restrict__ v, const float* __restrict__ Sc,
    float* __restrict__ y) {
  __shared__ float sQ[64 * 65];
  __shared__ float sKS[64 * 65];  // k-tilde (stride 65), later S (stride 64)
  __shared__ float sP[64 * 65];
  __shared__ float sV[64 * 64];
  int tid = threadIdx.x;
  int bhc = blockIdx.x;
  int c = bhc & 7, h = (bhc >> 3) & 31, b = bhc >> 8;
  size_t gbase = ((size_t)(b * Tz) + c * 64) * Cz + h * 64;
  size_t cbase = (size_t)bhc * 4096;

  // load qt, kt (bf16 -> f32, stride 65)
#pragma unroll
  for (int i = 0; i < 4; i++) {
    int i4 = tid + i * 256;  // 1024 quads
    int t = i4 >> 4, dq = i4 & 15;
    ushort4 qu = *(const ushort4*)&qt[cbase + i4 * 4];
    ushort4 ku = *(const ushort4*)&kt[cbase + i4 * 4];
    float* dstq = &sQ[t * 65 + dq * 4];
    float* dstk = &sKS[t * 65 + dq * 4];
    unsigned int uq[4] = {qu.x, qu.y, qu.z, qu.w};
    unsigned int uk[4] = {ku.x, ku.y, ku.z, ku.w};
#pragma unroll
    for (int e = 0; e < 4; e++) {
      unsigned int bq = uq[e] << 16;
      unsigned int bk = uk[e] << 16;
      dstq[e] = __builtin_bit_cast(float, bq);
      dstk[e] = __builtin_bit_cast(float, bk);
    }
  }
  __syncthreads();
  // P[t][s] = sum_d qt[t][d]*kt[s][d], causal mask s<=t
  int tg = tid & 15, sg = tid >> 4;
  float p[4][4];
#pragma unroll
  for (int i = 0; i < 4; i++)
#pragma unroll
    for (int jx = 0; jx < 4; jx++) p[i][jx] = 0.f;
  for (int d = 0; d < 64; d++) {
    float qv[4], kv[4];
#pragma unroll
    for (int i = 0; i < 4; i++) qv[i] = sQ[(tg * 4 + i) * 65 + d];
#pragma unroll
    for (int jx = 0; jx < 4; jx++) kv[jx] = sKS[(sg * 4 + jx) * 65 + d];
#pragma unroll
    for (int i = 0; i < 4; i++)
#pragma unroll
      for (int jx = 0; jx < 4; jx++) p[i][jx] += qv[i] * kv[jx];
  }
#pragma unroll
  for (int i = 0; i < 4; i++) {
    int t = tg * 4 + i;
#pragma unroll
    for (int jx = 0; jx < 4; jx++) {
      int s = sg * 4 + jx;
      sP[t * 65 + s] = (s <= t) ? p[i][jx] : 0.f;
    }
  }
  __syncthreads();
  // load S (stride 64, overwrites kt) and V
#pragma unroll
  for (int i = 0; i < 4; i++) {
    int i4 = tid + i * 256;
    int t = i4 >> 4, dq = i4 & 15;
    *(float4*)&sKS[t * 64 + dq * 4] = *(const float4*)&Sc[cbase + i4 * 4];
    *(float4*)&sV[t * 64 + dq * 4] =
        *(const float4*)&v[gbase + (size_t)t * Cz + dq * 4];
  }
  __syncthreads();
  // o[t][j] = sum_s P[t][s] V[s][j] + sum_d qt[t][d] S[d][j]
  f32x4 o[4];
#pragma unroll
  for (int i = 0; i < 4; i++) o[i] = (f32x4){0.f, 0.f, 0.f, 0.f};
  for (int s = 0; s < 64; s++) {
    f32x4 vv = *(const f32x4*)&sV[s * 64 + sg * 4];
#pragma unroll
    for (int i = 0; i < 4; i++) {
      float pv = sP[(tg * 4 + i) * 65 + s];
      o[i] += pv * vv;
    }
  }
  for (int d = 0; d < 64; d++) {
    f32x4 sv = *(const f32x4*)&sKS[d * 64 + sg * 4];
#pragma unroll
    for (int i = 0; i < 4; i++) {
      float qv = sQ[(tg * 4 + i) * 65 + d];
      o[i] += qv * sv;
    }
  }
#pragma unroll
  for (int i = 0; i < 4; i++) {
    int t = tg * 4 + i;
    *(f32x4*)&y[gbase + (size_t)t * Cz + sg * 4] = o[i];
  }
}

// ---------------------------------------------------------------------------
// LayerNorm over C, write bf16
__global__ __launch_bounds__(256) void k_ln(
    const float* __restrict__ y, const float* __restrict__ lg,
    const float* __restrict__ lb, bf16* __restrict__ yb) {
  __shared__ float red[8];
  int t = blockIdx.x;
  int tid = threadIdx.x;
  const float4* y4 = (const float4*)(y + (size_t)t * Cz);
  float4 vals[2];
  float s = 0.f, s2 = 0.f;
#pragma unroll
  for (int u = 0; u < 2; u++) {
    float4 a = y4[tid + 256 * u];
    vals[u] = a;
    s += a.x + a.y + a.z + a.w;
    s2 += a.x * a.x + a.y * a.y + a.z * a.z + a.w * a.w;
  }
#pragma unroll
  for (int off = 32; off > 0; off >>= 1) {
    s += __shfl_down(s, off);
    s2 += __shfl_down(s2, off);
  }
  if ((tid & 63) == 0) {
    red[(tid >> 6) * 2] = s;
    red[(tid >> 6) * 2 + 1] = s2;
  }
  __syncthreads();
  float ts = red[0] + red[2] + red[4] + red[6];
  float ts2 = red[1] + red[3] + red[5] + red[7];
  float mu = ts / (float)Cz;
  float var = ts2 / (float)Cz - mu * mu;
  float inv = rsqrtf(var + 1e-5f);
  bf16* outp = yb + (size_t)t * Cz;
#pragma unroll
  for (int u = 0; u < 2; u++) {
    int c0 = (tid + 256 * u) * 4;
    float4 a = vals[u];
    outp[c0 + 0] = __float2bfloat16((a.x - mu) * inv * lg[c0 + 0] + lb[c0 + 0]);
    outp[c0 + 1] = __float2bfloat16((a.y - mu) * inv * lg[c0 + 1] + lb[c0 + 1]);
    outp[c0 + 2] = __float2bfloat16((a.z - mu) * inv * lg[c0 + 2] + lb[c0 + 2]);
    outp[c0 + 3] = __float2bfloat16((a.w - mu) * inv * lg[c0 + 3] + lb[c0 + 3]);
  }
}

// ---------------------------------------------------------------------------
extern "C" void kernel_launch(void* const* d_in, const int* in_sizes, int n_in,
                              void* d_out, int out_size, void* d_ws,
                              size_t ws_size, hipStream_t stream) {
  const float* x      = (const float*)d_in[0];
  const float* maa_x  = (const float*)d_in[1];
  const float* maa_r  = (const float*)d_in[2];
  const float* maa_k  = (const float*)d_in[3];
  const float* maa_v  = (const float*)d_in[4];
  const float* maa_w  = (const float*)d_in[5];
  const float* maa_w1 = (const float*)d_in[6];
  const float* maa_w2 = (const float*)d_in[7];
  const float* tdcay  = (const float*)d_in[8];
  const float* td_w1  = (const float*)d_in[9];
  const float* td_w2  = (const float*)d_in[10];
  const float* q_w    = (const float*)d_in[11];
  const float* q_b    = (const float*)d_in[12];
  const float* k_w    = (const float*)d_in[13];
  const float* k_b    = (const float*)d_in[14];
  const float* v_w    = (const float*)d_in[15];
  const float* v_b    = (const float*)d_in[16];
  const float* ln_g   = (const float*)d_in[17];
  const float* ln_b   = (const float*)d_in[18];
  const float* o_w    = (const float*)d_in[19];
  float* out = (float*)d_out;

  char* p = (char*)d_ws;
  auto alloc = [&](size_t bytes) {
    char* r = p;
    p += (bytes + 255) & ~(size_t)255;
    return r;
  };
  const size_t WB = (size_t)Cz * Cz * sizeof(bf16);    // 8 MB
  const size_t AF = (size_t)NTOK * Cz * sizeof(float); // 8 MB
  const size_t AB = (size_t)NTOK * Cz * sizeof(bf16);  // 4 MB

  bf16* qwt = (bf16*)alloc(WB);
  bf16* kwt = (bf16*)alloc(WB);
  bf16* vwt = (bf16*)alloc(WB);
  bf16* owt = (bf16*)alloc(WB);
  float* dx  = (float*)alloc(AF);
  float* xxx = (float*)alloc(AF);
  float* mm  = (float*)alloc((size_t)NTOK * 128 * sizeof(float));
  bf16* xr = (bf16*)alloc(AB);
  bf16* xk = (bf16*)alloc(AB);
  bf16* xv = (bf16*)alloc(AB);
  float* xw = (float*)alloc(AF);
  float* tw = (float*)alloc((size_t)NTOK * 64 * sizeof(float));
  float* wlog = (float*)alloc(AF);
  float* kscl = (float*)alloc(AF);
  float* q = (float*)alloc(AF);
  float* k = (float*)alloc(AF);
  float* v = (float*)alloc(AF);
  float* y = (float*)alloc(AF);
  bf16* yb = (bf16*)alloc(AB);

  // chunked-scan buffers reuse dead arrays (all within this launch):
  bf16* qt = (bf16*)xxx;            // 4 MB (xxx dead after k_mm)
  bf16* kt = (bf16*)((char*)xxx + 4 * 1024 * 1024);  // 4 MB
  bf16* kh = (bf16*)dx;             // 4 MB (dx dead after k_mproj)
  float* U = xw;                    // 8 MB (xw dead after k_tdA)
  float* aLbuf = mm;                // 128 KB (mm dead after k_mproj)
  float* Scar = q;                  // 8 MB (q dead after k_chunk_prep)

  // 1. weight transpose+convert
  k_transpose<<<dim3(64, 64, 4), dim3(32, 8), 0, stream>>>(
      q_w, k_w, v_w, o_w, qwt, kwt, vwt, owt);
  // 2. token shift
  k_prep<<<2048, 256, 0, stream>>>(x, maa_x, dx, xxx);
  // 3. mix LoRA stage 1 (LDS-staged weights, 4 tok/block)
  k_mm<<<256, 256, 0, stream>>>(xxx, maa_w1, mm);
  // 4. mix LoRA stage 2 + fused xr/xk/xv/xw
  k_mproj<<<dim3(128, 8), 256, 0, stream>>>(mm, maa_w2, x, dx, maa_r, maa_k,
                                            maa_v, maa_w, xr, xk, xv, xw);
  // 5-6. decay LoRA
  k_tdA<<<256, 256, 0, stream>>>(xw, td_w1, tw);
  k_tdB<<<dim3(128, 8), 256, 0, stream>>>(tw, td_w2, tdcay, wlog, kscl);
  // 7. q,k,v projections (k scaled by 1-exp(wlog), q scaled by Dh^-0.5)
  k_gemm_qkv<<<dim3(16, 8, 3), 256, 0, stream>>>(
      xr, xk, xv, qwt, kwt, vwt, q_b, k_b, v_b, kscl, q, k, v);
  // 8. chunked GLA
  k_chunk_prep<<<512, 256, 0, stream>>>(q, k, v, wlog, qt, kt, kh, aLbuf, U);
  k_carry<<<256, 64, 0, stream>>>(aLbuf, U, Scar);
  k_chunk_out<<<512, 256, 0, stream>>>(qt, kt, v, Scar, y);
  // 9. LayerNorm -> bf16
  k_ln<<<NTOK, 256, 0, stream>>>(y, ln_g, ln_b, yb);
  // 10. output projection
  k_gemm_o<<<dim3(16, 8, 1), 256, 0, stream>>>(yb, owt, out);
}

// Round 4
// 361.786 us; speedup vs baseline: 1.6338x; 1.6338x over previous
//
#include <hip/hip_runtime.h>
#include <hip/hip_bf16.h>
#include <math.h>

// Problem constants
#define Bz 2
#define Tz 512
#define Cz 2048
#define Hh 32
#define DH 64
#define NTOK (Bz * Tz)   // 1024
#define NCH 8            // chunks per sequence (Tz/64)
#define NSLICE 16        // split-K slices for LoRA GEMMs (K-slice = 128)

typedef __hip_bfloat16 bf16;
typedef __attribute__((ext_vector_type(8))) short short8;
typedef __attribute__((ext_vector_type(4))) float f32x4;

// ---------------------------------------------------------------------------
// async global->LDS, 16B per lane. LDS dest must be wave-uniform base;
// lanes land at base + lane*16.
__device__ __forceinline__ void load_lds16(const void* g, void* l) {
  __builtin_amdgcn_global_load_lds(
      (const __attribute__((address_space(1))) unsigned int*)g,
      (__attribute__((address_space(3))) unsigned int*)l,
      16, 0, 0);
}

// ---------------------------------------------------------------------------
// Weight transpose + f32->bf16: Wt[n][k] = (bf16) W[k][n].  z selects weight.
__global__ __launch_bounds__(256) void k_transpose(
    const float* __restrict__ qw, const float* __restrict__ kw,
    const float* __restrict__ vw, const float* __restrict__ ow,
    bf16* __restrict__ qwt, bf16* __restrict__ kwt,
    bf16* __restrict__ vwt, bf16* __restrict__ owt) {
  __shared__ float tile[32][33];
  const float* W;
  bf16* O;
  switch (blockIdx.z) {
    case 0: W = qw; O = qwt; break;
    case 1: W = kw; O = kwt; break;
    case 2: W = vw; O = vwt; break;
    default: W = ow; O = owt; break;
  }
  int bx = blockIdx.x * 32, by = blockIdx.y * 32;
  int tx = threadIdx.x, ty = threadIdx.y;
#pragma unroll
  for (int i = 0; i < 4; i++)
    tile[ty + 8 * i][tx] = W[(size_t)(by + ty + 8 * i) * Cz + bx + tx];
  __syncthreads();
#pragma unroll
  for (int i = 0; i < 4; i++)
    O[(size_t)(bx + ty + 8 * i) * Cz + by + tx] =
        __float2bfloat16(tile[tx][ty + 8 * i]);
}

// ---------------------------------------------------------------------------
// LoRA weight transpose: maa_w1 [2048][128] -> w1t [128][2048] bf16,
// td_w1 [2048][64] -> tdw1t [64][2048] bf16.  grid (64, 6), block (32,8).
__global__ __launch_bounds__(256) void k_transpose_small(
    const float* __restrict__ w1, const float* __restrict__ tdw1,
    bf16* __restrict__ w1t, bf16* __restrict__ tdw1t) {
  __shared__ float tile[32][33];
  int z = blockIdx.y;
  const float* W;
  bf16* O;
  int N, ny;
  if (z < 4) { W = w1; O = w1t; N = 128; ny = z; }
  else       { W = tdw1; O = tdw1t; N = 64; ny = z - 4; }
  int bk = blockIdx.x * 32;  // K offset
  int bn = ny * 32;          // N offset
  int tx = threadIdx.x, ty = threadIdx.y;
#pragma unroll
  for (int i = 0; i < 4; i++)
    tile[ty + 8 * i][tx] = W[(size_t)(bk + ty + 8 * i) * N + bn + tx];
  __syncthreads();
#pragma unroll
  for (int i = 0; i < 4; i++)
    O[(size_t)(bn + ty + 8 * i) * Cz + bk + tx] =
        __float2bfloat16(tile[tx][ty + 8 * i]);
}

// ---------------------------------------------------------------------------
// dx = x_{t-1} - x_t (zero pad at t=0);  xxxb = bf16(x + dx*maa_x)
__global__ __launch_bounds__(256) void k_prep(
    const float* __restrict__ x, const float* __restrict__ maa_x,
    float* __restrict__ dx, bf16* __restrict__ xxxb) {
  int i4 = blockIdx.x * 256 + threadIdx.x;  // over 524288 float4
  int row = i4 >> 9;                        // 512 float4 per row
  int t = row & (Tz - 1);
  int c4 = i4 & 511;
  const float4* x4 = (const float4*)x;
  float4 xv = x4[i4];
  float4 xp = make_float4(0.f, 0.f, 0.f, 0.f);
  if (t != 0) xp = x4[i4 - 512];
  float4 mx = ((const float4*)maa_x)[c4];
  float4 d, xx;
  d.x = xp.x - xv.x; d.y = xp.y - xv.y; d.z = xp.z - xv.z; d.w = xp.w - xv.w;
  xx.x = xv.x + d.x * mx.x; xx.y = xv.y + d.y * mx.y;
  xx.z = xv.z + d.z * mx.z; xx.w = xv.w + d.w * mx.w;
  ((float4*)dx)[i4] = d;
  ushort4 u;
  u.x = __builtin_bit_cast(unsigned short, __float2bfloat16(xx.x));
  u.y = __builtin_bit_cast(unsigned short, __float2bfloat16(xx.y));
  u.z = __builtin_bit_cast(unsigned short, __float2bfloat16(xx.z));
  u.w = __builtin_bit_cast(unsigned short, __float2bfloat16(xx.w));
  ((ushort4*)xxxb)[i4] = u;
}

// ---------------------------------------------------------------------------
// Split-K MFMA GEMM for the skinny LoRA matmuls.
// part[slice][1024][NT] = A[M][K=2048] @ Bt[NT][K]^T  over K-slice of 128.
// MT in {128,256}; 4 waves arranged (MT/64) x (NT/64).
template <int MT, int NT>
__global__ __launch_bounds__(256) void k_lora_gemm(
    const bf16* __restrict__ A, const bf16* __restrict__ Bt,
    float* __restrict__ part) {
  constexpr int K = Cz;
  constexpr int KS = K / NSLICE;  // 128
  constexpr int WM = MT / 64;     // waves along M
  __shared__ alignas(16) bf16 As[MT * 32];
  __shared__ alignas(16) bf16 Bs[NT * 32];
  int tid = threadIdx.x;
  int lane = tid & 63, wave = tid >> 6;
  int wm = wave % WM, wn = wave / WM;
  int bM = blockIdx.x;
  int slice = blockIdx.y;
  int k0base = slice * KS;

  f32x4 acc[4][4];
#pragma unroll
  for (int i = 0; i < 4; i++)
#pragma unroll
    for (int j = 0; j < 4; j++) acc[i][j] = (f32x4){0.f, 0.f, 0.f, 0.f};

  int srow = lane >> 2;
  int scol = (lane & 3) * 8;
  int fr = lane & 15, fk = (lane >> 4) * 8;
  const bf16* rA = As + (wm * 64 + fr) * 32 + fk;
  const bf16* rB = Bs + (wn * 64 + fr) * 32 + fk;

  for (int kk = 0; kk < KS; kk += 32) {
    int k0 = k0base + kk;
#pragma unroll
    for (int i = 0; i < MT / 64; i++) {
      int r = wave * 16 + i * 64;  // wave-uniform strip
      load_lds16(A + (size_t)(bM * MT + r + srow) * K + k0 + scol, As + r * 32);
    }
#pragma unroll
    for (int i = 0; i < NT / 64; i++) {
      int r = wave * 16 + i * 64;
      load_lds16(Bt + (size_t)(r + srow) * K + k0 + scol, Bs + r * 32);
    }
    __syncthreads();
    short8 af[4], bf[4];
#pragma unroll
    for (int i = 0; i < 4; i++) af[i] = *(const short8*)(rA + i * 16 * 32);
#pragma unroll
    for (int j = 0; j < 4; j++) bf[j] = *(const short8*)(rB + j * 16 * 32);
#pragma unroll
    for (int i = 0; i < 4; i++)
#pragma unroll
      for (int j = 0; j < 4; j++)
        acc[i][j] = __builtin_amdgcn_mfma_f32_16x16x32_bf16(af[i], bf[j],
                                                            acc[i][j], 0, 0, 0);
    __syncthreads();
  }

  int r0 = (lane >> 4) * 4, cn = lane & 15;
  size_t pbase = (size_t)slice * NTOK * NT;
#pragma unroll
  for (int i = 0; i < 4; i++) {
    int m = bM * MT + wm * 64 + i * 16 + r0;
#pragma unroll
    for (int j = 0; j < 4; j++) {
      int n = wn * 64 + j * 16 + cn;
#pragma unroll
      for (int r = 0; r < 4; r++)
        part[pbase + (size_t)(m + r) * NT + n] = acc[i][j][r];
    }
  }
}

// ---------------------------------------------------------------------------
// out[i] = tanh(sum over NSLICE partials).  One float4 per thread.
__global__ __launch_bounds__(256) void k_reduce_tanh(
    const float* __restrict__ part, float* __restrict__ out, int n4) {
  int i = blockIdx.x * 256 + threadIdx.x;
  f32x4 s = (f32x4){0.f, 0.f, 0.f, 0.f};
#pragma unroll
  for (int sl = 0; sl < NSLICE; sl++)
    s += *(const f32x4*)&part[(size_t)sl * n4 * 4 + i * 4];
  float4 o;
  o.x = tanhf(s[0]); o.y = tanhf(s[1]); o.z = tanhf(s[2]); o.w = tanhf(s[3]);
  ((float4*)out)[i] = o;
}

// ---------------------------------------------------------------------------
// m_r = mm @ maa_w2[r]; fuse xr/xk/xv (bf16) and xwb (bf16) outputs.
// grid: (NTOK/8, Cz/256), block 256.
__global__ __launch_bounds__(256) void k_mproj(
    const float* __restrict__ mm, const float* __restrict__ w2,
    const float* __restrict__ x, const float* __restrict__ dx,
    const float* __restrict__ maa_r, const float* __restrict__ maa_k,
    const float* __restrict__ maa_v, const float* __restrict__ maa_w,
    bf16* __restrict__ pxr, bf16* __restrict__ pxk,
    bf16* __restrict__ pxv, bf16* __restrict__ pxw) {
  __shared__ float sM[8][128];
  int tid = threadIdx.x;
  int tok0 = blockIdx.x * 8;
  int c = blockIdx.y * 256 + tid;
#pragma unroll
  for (int u = 0; u < 4; u++) {
    int idx = tid + 256 * u;
    sM[idx >> 7][idx & 127] = mm[(size_t)tok0 * 128 + idx];
  }
  __syncthreads();
  float m_[4][8];
#pragma unroll
  for (int r = 0; r < 4; r++)
#pragma unroll
    for (int t = 0; t < 8; t++) m_[r][t] = 0.f;
#pragma unroll
  for (int r = 0; r < 4; r++) {
#pragma unroll 8
    for (int d = 0; d < 32; d++) {
      float w = w2[(size_t)(r * 32 + d) * Cz + c];
#pragma unroll
      for (int t = 0; t < 8; t++) m_[r][t] += w * sM[t][r * 32 + d];
    }
  }
  float mr = maa_r[c], mk = maa_k[c], mv = maa_v[c], mw = maa_w[c];
#pragma unroll
  for (int t = 0; t < 8; t++) {
    size_t idx = (size_t)(tok0 + t) * Cz + c;
    float xval = x[idx], dval = dx[idx];
    pxr[idx] = __float2bfloat16(xval + dval * (mr + m_[0][t]));
    pxk[idx] = __float2bfloat16(xval + dval * (mk + m_[1][t]));
    pxv[idx] = __float2bfloat16(xval + dval * (mv + m_[2][t]));
    pxw[idx] = __float2bfloat16(xval + dval * (mw + m_[3][t]));
  }
}

// ---------------------------------------------------------------------------
// w_log = max(-exp(td + tw @ td_w2), -5); write wlog (f32) and ksc = 1-exp(wlog)
// grid: (NTOK/8, Cz/256)
__global__ __launch_bounds__(256) void k_tdB(
    const float* __restrict__ tw, const float* __restrict__ w2,
    const float* __restrict__ td, float* __restrict__ wlog,
    float* __restrict__ ksc) {
  __shared__ float sT[8][64];
  int tid = threadIdx.x;
  int tok0 = blockIdx.x * 8;
  int c = blockIdx.y * 256 + tid;
#pragma unroll
  for (int u = 0; u < 2; u++) {
    int idx = tid + 256 * u;
    sT[idx >> 6][idx & 63] = tw[(size_t)tok0 * 64 + idx];
  }
  __syncthreads();
  float acc[8];
#pragma unroll
  for (int t = 0; t < 8; t++) acc[t] = 0.f;
#pragma unroll 8
  for (int d = 0; d < 64; d++) {
    float w = w2[(size_t)d * Cz + c];
#pragma unroll
    for (int t = 0; t < 8; t++) acc[t] += w * sT[t][d];
  }
  float tdc = td[c];
#pragma unroll
  for (int t = 0; t < 8; t++) {
    float wl = -expf(tdc + acc[t]);
    wl = fmaxf(wl, -5.0f);
    size_t idx = (size_t)(tok0 + t) * Cz + c;
    wlog[idx] = wl;
    ksc[idx] = 1.f - expf(wl);
  }
}

// ---------------------------------------------------------------------------
// m97-style bf16 MFMA GEMM: out[M=1024][N=2048] = A[M][K=2048] @ Wt[N][K]^T
__device__ __forceinline__ void gemm_tile(
    const bf16* __restrict__ A, const bf16* __restrict__ Wt,
    const float* __restrict__ bias, const float* __restrict__ kscale,
    float scl, float* __restrict__ out, int bM, int bN) {
  constexpr int K = Cz, N = Cz;
  __shared__ alignas(16) bf16 As[128 * 32];
  __shared__ alignas(16) bf16 Bs[128 * 32];
  int tid = threadIdx.x;
  int lane = tid & 63, wave = tid >> 6;
  int wm = wave & 1, wn = wave >> 1;

  f32x4 acc[4][4];
#pragma unroll
  for (int i = 0; i < 4; i++)
#pragma unroll
    for (int j = 0; j < 4; j++) acc[i][j] = (f32x4){0.f, 0.f, 0.f, 0.f};

  int srow = lane >> 2;
  int scol = (lane & 3) * 8;
  const bf16* gA = A + (size_t)(bM * 128 + wave * 16 + srow) * K + scol;
  const bf16* gB = Wt + (size_t)(bN * 128 + wave * 16 + srow) * K + scol;
  bf16* lA = As + (wave * 16) * 32;
  bf16* lB = Bs + (wave * 16) * 32;

  int fr = lane & 15, fk = (lane >> 4) * 8;
  const bf16* rA = As + (wm * 64 + fr) * 32 + fk;
  const bf16* rB = Bs + (wn * 64 + fr) * 32 + fk;

  for (int k0 = 0; k0 < K; k0 += 32) {
    load_lds16(gA + k0, lA);
    load_lds16(gA + (size_t)64 * K + k0, lA + 64 * 32);
    load_lds16(gB + k0, lB);
    load_lds16(gB + (size_t)64 * K + k0, lB + 64 * 32);
    __syncthreads();
    short8 af[4], bf[4];
#pragma unroll
    for (int i = 0; i < 4; i++) af[i] = *(const short8*)(rA + i * 16 * 32);
#pragma unroll
    for (int j = 0; j < 4; j++) bf[j] = *(const short8*)(rB + j * 16 * 32);
#pragma unroll
    for (int i = 0; i < 4; i++)
#pragma unroll
      for (int j = 0; j < 4; j++)
        acc[i][j] = __builtin_amdgcn_mfma_f32_16x16x32_bf16(af[i], bf[j],
                                                            acc[i][j], 0, 0, 0);
    __syncthreads();
  }

  int r0 = (lane >> 4) * 4;
  int cn = lane & 15;
#pragma unroll
  for (int i = 0; i < 4; i++) {
    int mbase = bM * 128 + wm * 64 + i * 16 + r0;
#pragma unroll
    for (int j = 0; j < 4; j++) {
      int n = bN * 128 + wn * 64 + j * 16 + cn;
      float bv = bias ? bias[n] : 0.f;
#pragma unroll
      for (int r = 0; r < 4; r++) {
        float vv = (acc[i][j][r] + bv) * scl;
        size_t oi = (size_t)(mbase + r) * N + n;
        if (kscale) vv *= kscale[oi];
        out[oi] = vv;
      }
    }
  }
}

__global__ __launch_bounds__(256) void k_gemm_qkv(
    const bf16* __restrict__ xr, const bf16* __restrict__ xk,
    const bf16* __restrict__ xv, const bf16* __restrict__ qwt,
    const bf16* __restrict__ kwt, const bf16* __restrict__ vwt,
    const float* __restrict__ qb, const float* __restrict__ kb,
    const float* __restrict__ vb, const float* __restrict__ kscl,
    float* __restrict__ q, float* __restrict__ k, float* __restrict__ v) {
  const bf16 *A, *W;
  const float* b;
  const float* ks = nullptr;
  float* o;
  float scl = 1.f;
  if (blockIdx.z == 0) {
    A = xr; W = qwt; b = qb; o = q; scl = 0.125f;  // fold Dh^-0.5 into q
  } else if (blockIdx.z == 1) {
    A = xk; W = kwt; b = kb; o = k; ks = kscl;
  } else {
    A = xv; W = vwt; b = vb; o = v;
  }
  gemm_tile(A, W, b, ks, scl, o, blockIdx.y, blockIdx.x);
}

__global__ __launch_bounds__(256) void k_gemm_o(
    const bf16* __restrict__ yb, const bf16* __restrict__ owt,
    float* __restrict__ out) {
  gemm_tile(yb, owt, nullptr, nullptr, 1.f, out, blockIdx.y, blockIdx.x);
}

// ---------------------------------------------------------------------------
// Chunked GLA pass 1: per (b,h,chunk of 64): cumsum of wlog; emit
// qt = q*exp(cum), kt = k*exp(-cum), kh = k*exp(cumL-cum) (bf16, chunk-major),
// aL[d] = exp(cumL), and U[d][j] = sum_s kh[s][d]*v[s][j].
__global__ __launch_bounds__(256) void k_chunk_prep(
    const float* __restrict__ q, const float* __restrict__ k,
    const float* __restrict__ v, const float* __restrict__ wlog,
    bf16* __restrict__ qt, bf16* __restrict__ kt, bf16* __restrict__ kh,
    float* __restrict__ aL, float* __restrict__ U) {
  __shared__ float sCum[64 * 64];
  __shared__ float sKh[64 * 64];
  __shared__ float sV[64 * 64];
  int tid = threadIdx.x;
  int bhc = blockIdx.x;
  int c = bhc & 7, h = (bhc >> 3) & 31, b = bhc >> 8;
  size_t gbase = ((size_t)(b * Tz) + c * 64) * Cz + h * 64;
  size_t cbase = (size_t)bhc * 4096;

#pragma unroll
  for (int i = 0; i < 4; i++) {
    int i4 = tid + i * 256;           // 1024 float4
    int t = i4 >> 4, dq = i4 & 15;
    size_t g = gbase + (size_t)t * Cz + dq * 4;
    *(float4*)&sCum[t * 64 + dq * 4] = *(const float4*)&wlog[g];
    *(float4*)&sKh[t * 64 + dq * 4] = *(const float4*)&k[g];
    *(float4*)&sV[t * 64 + dq * 4] = *(const float4*)&v[g];
  }
  __syncthreads();
  if (tid < 64) {
    float cum = 0.f;
#pragma unroll
    for (int t = 0; t < 64; t++) {
      cum += sCum[t * 64 + tid];
      sCum[t * 64 + tid] = cum;
    }
  }
  __syncthreads();
#pragma unroll
  for (int i = 0; i < 16; i++) {
    int idx = tid + i * 256;
    int t = idx >> 6, d = idx & 63;
    float cl = sCum[t * 64 + d];
    float cL = sCum[63 * 64 + d];
    float kraw = sKh[t * 64 + d];
    float qv = q[gbase + (size_t)t * Cz + d];
    float khv = kraw * expf(cL - cl);
    qt[cbase + idx] = __float2bfloat16(qv * expf(cl));
    kt[cbase + idx] = __float2bfloat16(kraw * expf(-cl));
    kh[cbase + idx] = __float2bfloat16(khv);
    sKh[t * 64 + d] = khv;
    if (t == 63) aL[(size_t)bhc * 64 + d] = expf(cl);
  }
  __syncthreads();
  int j = tid & 63, dg = tid >> 6;
  float acc[16];
#pragma unroll
  for (int dd = 0; dd < 16; dd++) acc[dd] = 0.f;
  for (int s = 0; s < 64; s++) {
    float vs = sV[s * 64 + j];
#pragma unroll
    for (int dd = 0; dd < 16; dd++)
      acc[dd] += sKh[s * 64 + dg * 16 + dd] * vs;
  }
#pragma unroll
  for (int dd = 0; dd < 16; dd++)
    U[cbase + (size_t)(dg * 16 + dd) * 64 + j] = acc[dd];
}

// ---------------------------------------------------------------------------
// Chunked GLA pass 2 (sequential over 8 chunks): S_{c+1} = diag(aL)*S_c + U_c.
__global__ __launch_bounds__(64) void k_carry(
    const float* __restrict__ aL, const float* __restrict__ U,
    float* __restrict__ Sc) {
  int bh = blockIdx.x >> 2;
  int jg = blockIdx.x & 3;
  int tid = threadIdx.x;
  int jj = tid & 15, dg = tid >> 4;
  int j = jg * 16 + jj;
  float S[16];
#pragma unroll
  for (int dd = 0; dd < 16; dd++) S[dd] = 0.f;
  for (int c = 0; c < NCH; c++) {
    int bhc = bh * NCH + c;
    size_t base = (size_t)bhc * 4096;
#pragma unroll
    for (int dd = 0; dd < 16; dd++) {
      int d = dg * 16 + dd;
      Sc[base + (size_t)d * 64 + j] = S[dd];
      S[dd] = S[dd] * aL[(size_t)bhc * 64 + d] + U[base + (size_t)d * 64 + j];
    }
  }
}

// ---------------------------------------------------------------------------
// Chunked GLA pass 3: o = mask(qt @ kt^T) @ V + qt @ S_c.  512 blocks.
__global__ __launch_bounds__(256) void k_chunk_out(
    const bf16* __restrict__ qt, const bf16* __restrict__ kt,
    const float* __restrict__ v, const float* __restrict__ Sc,
    float* __restrict__ y) {
  __shared__ float sQ[64 * 65];
  __shared__ float sKS[64 * 65];  // k-tilde (stride 65), later S (stride 64)
  __shared__ float sP[64 * 65];
  __shared__ float sV[64 * 64];
  int tid = threadIdx.x;
  int bhc = blockIdx.x;
  int c = bhc & 7, h = (bhc >> 3) & 31, b = bhc >> 8;
  size_t gbase = ((size_t)(b * Tz) + c * 64) * Cz + h * 64;
  size_t cbase = (size_t)bhc * 4096;

#pragma unroll
  for (int i = 0; i < 4; i++) {
    int i4 = tid + i * 256;  // 1024 quads
    int t = i4 >> 4, dq = i4 & 15;
    ushort4 qu = *(const ushort4*)&qt[cbase + i4 * 4];
    ushort4 ku = *(const ushort4*)&kt[cbase + i4 * 4];
    float* dstq = &sQ[t * 65 + dq * 4];
    float* dstk = &sKS[t * 65 + dq * 4];
    unsigned int uq[4] = {qu.x, qu.y, qu.z, qu.w};
    unsigned int uk[4] = {ku.x, ku.y, ku.z, ku.w};
#pragma unroll
    for (int e = 0; e < 4; e++) {
      unsigned int bq = uq[e] << 16;
      unsigned int bk = uk[e] << 16;
      dstq[e] = __builtin_bit_cast(float, bq);
      dstk[e] = __builtin_bit_cast(float, bk);
    }
  }
  __syncthreads();
  int tg = tid & 15, sg = tid >> 4;
  float p[4][4];
#pragma unroll
  for (int i = 0; i < 4; i++)
#pragma unroll
    for (int jx = 0; jx < 4; jx++) p[i][jx] = 0.f;
  for (int d = 0; d < 64; d++) {
    float qv[4], kv[4];
#pragma unroll
    for (int i = 0; i < 4; i++) qv[i] = sQ[(tg * 4 + i) * 65 + d];
#pragma unroll
    for (int jx = 0; jx < 4; jx++) kv[jx] = sKS[(sg * 4 + jx) * 65 + d];
#pragma unroll
    for (int i = 0; i < 4; i++)
#pragma unroll
      for (int jx = 0; jx < 4; jx++) p[i][jx] += qv[i] * kv[jx];
  }
#pragma unroll
  for (int i = 0; i < 4; i++) {
    int t = tg * 4 + i;
#pragma unroll
    for (int jx = 0; jx < 4; jx++) {
      int s = sg * 4 + jx;
      sP[t * 65 + s] = (s <= t) ? p[i][jx] : 0.f;
    }
  }
  __syncthreads();
#pragma unroll
  for (int i = 0; i < 4; i++) {
    int i4 = tid + i * 256;
    int t = i4 >> 4, dq = i4 & 15;
    *(float4*)&sKS[t * 64 + dq * 4] = *(const float4*)&Sc[cbase + i4 * 4];
    *(float4*)&sV[t * 64 + dq * 4] =
        *(const float4*)&v[gbase + (size_t)t * Cz + dq * 4];
  }
  __syncthreads();
  f32x4 o[4];
#pragma unroll
  for (int i = 0; i < 4; i++) o[i] = (f32x4){0.f, 0.f, 0.f, 0.f};
  for (int s = 0; s < 64; s++) {
    f32x4 vv = *(const f32x4*)&sV[s * 64 + sg * 4];
#pragma unroll
    for (int i = 0; i < 4; i++) {
      float pv = sP[(tg * 4 + i) * 65 + s];
      o[i] += pv * vv;
    }
  }
  for (int d = 0; d < 64; d++) {
    f32x4 sv = *(const f32x4*)&sKS[d * 64 + sg * 4];
#pragma unroll
    for (int i = 0; i < 4; i++) {
      float qv = sQ[(tg * 4 + i) * 65 + d];
      o[i] += qv * sv;
    }
  }
#pragma unroll
  for (int i = 0; i < 4; i++) {
    int t = tg * 4 + i;
    *(f32x4*)&y[gbase + (size_t)t * Cz + sg * 4] = o[i];
  }
}

// ---------------------------------------------------------------------------
// LayerNorm over C, write bf16
__global__ __launch_bounds__(256) void k_ln(
    const float* __restrict__ y, const float* __restrict__ lg,
    const float* __restrict__ lb, bf16* __restrict__ yb) {
  __shared__ float red[8];
  int t = blockIdx.x;
  int tid = threadIdx.x;
  const float4* y4 = (const float4*)(y + (size_t)t * Cz);
  float4 vals[2];
  float s = 0.f, s2 = 0.f;
#pragma unroll
  for (int u = 0; u < 2; u++) {
    float4 a = y4[tid + 256 * u];
    vals[u] = a;
    s += a.x + a.y + a.z + a.w;
    s2 += a.x * a.x + a.y * a.y + a.z * a.z + a.w * a.w;
  }
#pragma unroll
  for (int off = 32; off > 0; off >>= 1) {
    s += __shfl_down(s, off);
    s2 += __shfl_down(s2, off);
  }
  if ((tid & 63) == 0) {
    red[(tid >> 6) * 2] = s;
    red[(tid >> 6) * 2 + 1] = s2;
  }
  __syncthreads();
  float ts = red[0] + red[2] + red[4] + red[6];
  float ts2 = red[1] + red[3] + red[5] + red[7];
  float mu = ts / (float)Cz;
  float var = ts2 / (float)Cz - mu * mu;
  float inv = rsqrtf(var + 1e-5f);
  bf16* outp = yb + (size_t)t * Cz;
#pragma unroll
  for (int u = 0; u < 2; u++) {
    int c0 = (tid + 256 * u) * 4;
    float4 a = vals[u];
    outp[c0 + 0] = __float2bfloat16((a.x - mu) * inv * lg[c0 + 0] + lb[c0 + 0]);
    outp[c0 + 1] = __float2bfloat16((a.y - mu) * inv * lg[c0 + 1] + lb[c0 + 1]);
    outp[c0 + 2] = __float2bfloat16((a.z - mu) * inv * lg[c0 + 2] + lb[c0 + 2]);
    outp[c0 + 3] = __float2bfloat16((a.w - mu) * inv * lg[c0 + 3] + lb[c0 + 3]);
  }
}

// ---------------------------------------------------------------------------
extern "C" void kernel_launch(void* const* d_in, const int* in_sizes, int n_in,
                              void* d_out, int out_size, void* d_ws,
                              size_t ws_size, hipStream_t stream) {
  const float* x      = (const float*)d_in[0];
  const float* maa_x  = (const float*)d_in[1];
  const float* maa_r  = (const float*)d_in[2];
  const float* maa_k  = (const float*)d_in[3];
  const float* maa_v  = (const float*)d_in[4];
  const float* maa_w  = (const float*)d_in[5];
  const float* maa_w1 = (const float*)d_in[6];
  const float* maa_w2 = (const float*)d_in[7];
  const float* tdcay  = (const float*)d_in[8];
  const float* td_w1  = (const float*)d_in[9];
  const float* td_w2  = (const float*)d_in[10];
  const float* q_w    = (const float*)d_in[11];
  const float* q_b    = (const float*)d_in[12];
  const float* k_w    = (const float*)d_in[13];
  const float* k_b    = (const float*)d_in[14];
  const float* v_w    = (const float*)d_in[15];
  const float* v_b    = (const float*)d_in[16];
  const float* ln_g   = (const float*)d_in[17];
  const float* ln_b   = (const float*)d_in[18];
  const float* o_w    = (const float*)d_in[19];
  float* out = (float*)d_out;

  char* p = (char*)d_ws;
  auto alloc = [&](size_t bytes) {
    char* r = p;
    p += (bytes + 255) & ~(size_t)255;
    return r;
  };
  const size_t WB = (size_t)Cz * Cz * sizeof(bf16);    // 8 MB
  const size_t AF = (size_t)NTOK * Cz * sizeof(float); // 8 MB
  const size_t AB = (size_t)NTOK * Cz * sizeof(bf16);  // 4 MB

  bf16* qwt = (bf16*)alloc(WB);
  bf16* kwt = (bf16*)alloc(WB);
  bf16* vwt = (bf16*)alloc(WB);
  bf16* owt = (bf16*)alloc(WB);
  float* dx   = (float*)alloc(AF);
  char* xslot = (char*)alloc(AF);   // 8 MB multi-use
  float* mm  = (float*)alloc((size_t)NTOK * 128 * sizeof(float));
  bf16* xr = (bf16*)alloc(AB);
  bf16* xk = (bf16*)alloc(AB);
  bf16* xv = (bf16*)alloc(AB);
  char* xwslot = (char*)alloc(AF);  // 8 MB multi-use
  float* tw = (float*)alloc((size_t)NTOK * 64 * sizeof(float));
  float* wlog = (float*)alloc(AF);
  float* kscl = (float*)alloc(AF);
  float* q = (float*)alloc(AF);
  float* k = (float*)alloc(AF);
  float* v = (float*)alloc(AF);
  float* y = (float*)alloc(AF);
  bf16* yb = (bf16*)alloc(AB);

  // xslot: [0,4M) xxxb (steps 2-3) then qt (step 8+);
  //        [4M,4.5M) w1t (steps 1b-3); [4.5M,4.75M) tdw1t (steps 1b-5);
  //        [4M,8M) kt (step 8+).
  bf16* xxxb = (bf16*)xslot;
  bf16* w1t = (bf16*)(xslot + 4 * 1024 * 1024);
  bf16* tdw1t = (bf16*)(xslot + 4 * 1024 * 1024 + 512 * 1024);
  bf16* qt = (bf16*)xslot;
  bf16* kt = (bf16*)(xslot + 4 * 1024 * 1024);
  // xwslot: [0,4M) xwb (steps 4-5), then U full 8 MB (step 8+).
  bf16* xwb = (bf16*)xwslot;
  float* U = (float*)xwslot;
  // q slot: mm_part (steps 3-3b, 16*512KB = 8 MB), then q (7+), Scar (8.5+)
  float* mm_part = q;
  float* Scar = q;
  // k slot: tw_part (steps 5-5b, 4 MB), then k (7+)
  float* tw_part = k;
  bf16* kh = (bf16*)dx;   // dx dead after k_mproj
  float* aLbuf = mm;      // mm dead after k_mproj

  // 1. weight transpose+convert
  k_transpose<<<dim3(64, 64, 4), dim3(32, 8), 0, stream>>>(
      q_w, k_w, v_w, o_w, qwt, kwt, vwt, owt);
  k_transpose_small<<<dim3(64, 6), dim3(32, 8), 0, stream>>>(
      maa_w1, td_w1, w1t, tdw1t);
  // 2. token shift
  k_prep<<<2048, 256, 0, stream>>>(x, maa_x, dx, xxxb);
  // 3. mix LoRA stage 1: split-K MFMA + reduce/tanh
  k_lora_gemm<128, 128><<<dim3(8, NSLICE), 256, 0, stream>>>(xxxb, w1t, mm_part);
  k_reduce_tanh<<<128, 256, 0, stream>>>(mm_part, mm, NTOK * 128 / 4);
  // 4. mix LoRA stage 2 + fused xr/xk/xv/xwb
  k_mproj<<<dim3(128, 8), 256, 0, stream>>>(mm, maa_w2, x, dx, maa_r, maa_k,
                                            maa_v, maa_w, xr, xk, xv, xwb);
  // 5. decay LoRA stage 1: split-K MFMA + reduce/tanh
  k_lora_gemm<256, 64><<<dim3(4, NSLICE), 256, 0, stream>>>(xwb, tdw1t, tw_part);
  k_reduce_tanh<<<64, 256, 0, stream>>>(tw_part, tw, NTOK * 64 / 4);
  // 6. decay LoRA stage 2
  k_tdB<<<dim3(128, 8), 256, 0, stream>>>(tw, td_w2, tdcay, wlog, kscl);
  // 7. q,k,v projections (k scaled by 1-exp(wlog), q scaled by Dh^-0.5)
  k_gemm_qkv<<<dim3(16, 8, 3), 256, 0, stream>>>(
      xr, xk, xv, qwt, kwt, vwt, q_b, k_b, v_b, kscl, q, k, v);
  // 8. chunked GLA
  k_chunk_prep<<<512, 256, 0, stream>>>(q, k, v, wlog, qt, kt, kh, aLbuf, U);
  k_carry<<<256, 64, 0, stream>>>(aLbuf, U, Scar);
  k_chunk_out<<<512, 256, 0, stream>>>(qt, kt, v, Scar, y);
  // 9. LayerNorm -> bf16
  k_ln<<<NTOK, 256, 0, stream>>>(y, ln_g, ln_b, yb);
  // 10. output projection
  k_gemm_o<<<dim3(16, 8, 1), 256, 0, stream>>>(yb, owt, out);
}

// Round 5
// 355.466 us; speedup vs baseline: 1.6628x; 1.0178x over previous
//
#include <hip/hip_runtime.h>
#include <hip/hip_bf16.h>
#include <math.h>

// Problem constants
#define Bz 2
#define Tz 512
#define Cz 2048
#define Hh 32
#define DH 64
#define NTOK (Bz * Tz)   // 1024
#define NCH 8            // chunks per sequence (Tz/64)
#define NSLICE 32        // split-K slices for LoRA GEMMs (K-slice = 64)

typedef __hip_bfloat16 bf16;
typedef __attribute__((ext_vector_type(8))) short short8;
typedef __attribute__((ext_vector_type(4))) float f32x4;

// ---------------------------------------------------------------------------
// async global->LDS, 16B per lane. LDS dest must be wave-uniform base;
// lanes land at base + lane*16.
__device__ __forceinline__ void load_lds16(const void* g, void* l) {
  __builtin_amdgcn_global_load_lds(
      (const __attribute__((address_space(1))) unsigned int*)g,
      (__attribute__((address_space(3))) unsigned int*)l,
      16, 0, 0);
}

// ---------------------------------------------------------------------------
// Shared MFMA GEMM core: A[M][K=2048] @ Bt[N][K]^T over k in [kBeg,kEnd).
// 4 waves arranged 2x2; wave tile (MT/2)x(NT/2); 16x16x32 bf16 MFMA.
template <int MT, int NT>
__device__ __forceinline__ void gemm_core(
    const bf16* __restrict__ A, const bf16* __restrict__ Bt,
    int M0, int N0, int kBeg, int kEnd,
    f32x4 (&acc)[MT / 32][NT / 32]) {
  constexpr int AI = MT / 32, BJ = NT / 32;
  constexpr int TSA = MT / 16, TS = (MT + NT) / 16;
  static_assert(TS % 4 == 0, "strips must divide among 4 waves");
  __shared__ alignas(16) bf16 As[MT * 32];
  __shared__ alignas(16) bf16 Bs[NT * 32];
  int tid = threadIdx.x, lane = tid & 63, wave = tid >> 6;
  int wm = wave & 1, wn = wave >> 1;
  int srow = lane >> 2, scol = (lane & 3) * 8;
  int fr = lane & 15, fk = (lane >> 4) * 8;
  const bf16* rA = As + (wm * (MT / 2) + fr) * 32 + fk;
  const bf16* rB = Bs + (wn * (NT / 2) + fr) * 32 + fk;

  for (int k0 = kBeg; k0 < kEnd; k0 += 32) {
#pragma unroll
    for (int s = wave; s < TS; s += 4) {
      if (s < TSA)
        load_lds16(A + (size_t)(M0 + s * 16 + srow) * Cz + k0 + scol,
                   As + s * 16 * 32);
      else
        load_lds16(Bt + (size_t)(N0 + (s - TSA) * 16 + srow) * Cz + k0 + scol,
                   Bs + (s - TSA) * 16 * 32);
    }
    __syncthreads();
    short8 af[AI], bf[BJ];
#pragma unroll
    for (int i = 0; i < AI; i++) af[i] = *(const short8*)(rA + i * 16 * 32);
#pragma unroll
    for (int j = 0; j < BJ; j++) bf[j] = *(const short8*)(rB + j * 16 * 32);
#pragma unroll
    for (int i = 0; i < AI; i++)
#pragma unroll
      for (int j = 0; j < BJ; j++)
        acc[i][j] = __builtin_amdgcn_mfma_f32_16x16x32_bf16(af[i], bf[j],
                                                            acc[i][j], 0, 0, 0);
    __syncthreads();
  }
}

// ---------------------------------------------------------------------------
// Weight transpose + f32->bf16: Wt[n][k] = (bf16) W[k][n].  z selects weight.
__global__ __launch_bounds__(256) void k_transpose(
    const float* __restrict__ qw, const float* __restrict__ kw,
    const float* __restrict__ vw, const float* __restrict__ ow,
    bf16* __restrict__ qwt, bf16* __restrict__ kwt,
    bf16* __restrict__ vwt, bf16* __restrict__ owt) {
  __shared__ float tile[32][33];
  const float* W;
  bf16* O;
  switch (blockIdx.z) {
    case 0: W = qw; O = qwt; break;
    case 1: W = kw; O = kwt; break;
    case 2: W = vw; O = vwt; break;
    default: W = ow; O = owt; break;
  }
  int bx = blockIdx.x * 32, by = blockIdx.y * 32;
  int tx = threadIdx.x, ty = threadIdx.y;
#pragma unroll
  for (int i = 0; i < 4; i++)
    tile[ty + 8 * i][tx] = W[(size_t)(by + ty + 8 * i) * Cz + bx + tx];
  __syncthreads();
#pragma unroll
  for (int i = 0; i < 4; i++)
    O[(size_t)(bx + ty + 8 * i) * Cz + by + tx] =
        __float2bfloat16(tile[tx][ty + 8 * i]);
}

// ---------------------------------------------------------------------------
// LoRA weight transpose: maa_w1 [2048][128] -> w1t [128][2048] bf16,
// td_w1 [2048][64] -> tdw1t [64][2048] bf16.  grid (64, 6), block (32,8).
__global__ __launch_bounds__(256) void k_transpose_small(
    const float* __restrict__ w1, const float* __restrict__ tdw1,
    bf16* __restrict__ w1t, bf16* __restrict__ tdw1t) {
  __shared__ float tile[32][33];
  int z = blockIdx.y;
  const float* W;
  bf16* O;
  int N, ny;
  if (z < 4) { W = w1; O = w1t; N = 128; ny = z; }
  else       { W = tdw1; O = tdw1t; N = 64; ny = z - 4; }
  int bk = blockIdx.x * 32;  // K offset
  int bn = ny * 32;          // N offset
  int tx = threadIdx.x, ty = threadIdx.y;
#pragma unroll
  for (int i = 0; i < 4; i++)
    tile[ty + 8 * i][tx] = W[(size_t)(bk + ty + 8 * i) * N + bn + tx];
  __syncthreads();
#pragma unroll
  for (int i = 0; i < 4; i++)
    O[(size_t)(bn + ty + 8 * i) * Cz + bk + tx] =
        __float2bfloat16(tile[tx][ty + 8 * i]);
}

// ---------------------------------------------------------------------------
// dx = x_{t-1} - x_t (zero pad at t=0);  xxxb = bf16(x + dx*maa_x)
__global__ __launch_bounds__(256) void k_prep(
    const float* __restrict__ x, const float* __restrict__ maa_x,
    float* __restrict__ dx, bf16* __restrict__ xxxb) {
  int i4 = blockIdx.x * 256 + threadIdx.x;  // over 524288 float4
  int row = i4 >> 9;                        // 512 float4 per row
  int t = row & (Tz - 1);
  int c4 = i4 & 511;
  const float4* x4 = (const float4*)x;
  float4 xv = x4[i4];
  float4 xp = make_float4(0.f, 0.f, 0.f, 0.f);
  if (t != 0) xp = x4[i4 - 512];
  float4 mx = ((const float4*)maa_x)[c4];
  float4 d, xx;
  d.x = xp.x - xv.x; d.y = xp.y - xv.y; d.z = xp.z - xv.z; d.w = xp.w - xv.w;
  xx.x = xv.x + d.x * mx.x; xx.y = xv.y + d.y * mx.y;
  xx.z = xv.z + d.z * mx.z; xx.w = xv.w + d.w * mx.w;
  ((float4*)dx)[i4] = d;
  ushort4 u;
  u.x = __builtin_bit_cast(unsigned short, __float2bfloat16(xx.x));
  u.y = __builtin_bit_cast(unsigned short, __float2bfloat16(xx.y));
  u.z = __builtin_bit_cast(unsigned short, __float2bfloat16(xx.z));
  u.w = __builtin_bit_cast(unsigned short, __float2bfloat16(xx.w));
  ((ushort4*)xxxb)[i4] = u;
}

// ---------------------------------------------------------------------------
// Split-K LoRA GEMM: part[slice][1024][NT] += A @ Bt^T over K-slice of 64.
// grid (M-tiles=8, NSLICE).
template <int NT>
__global__ __launch_bounds__(256) void k_lora_gemm(
    const bf16* __restrict__ A, const bf16* __restrict__ Bt,
    float* __restrict__ part) {
  constexpr int KS = Cz / NSLICE;  // 64
  f32x4 acc[4][NT / 32];
#pragma unroll
  for (int i = 0; i < 4; i++)
#pragma unroll
    for (int j = 0; j < NT / 32; j++) acc[i][j] = (f32x4){0.f, 0.f, 0.f, 0.f};
  int bM = blockIdx.x, slice = blockIdx.y;
  gemm_core<128, NT>(A, Bt, bM * 128, 0, slice * KS, slice * KS + KS, acc);
  int lane = threadIdx.x & 63, wave = threadIdx.x >> 6;
  int wm = wave & 1, wn = wave >> 1;
  int r0 = (lane >> 4) * 4, cn = lane & 15;
#pragma unroll
  for (int i = 0; i < 4; i++) {
    int m = bM * 128 + wm * 64 + i * 16 + r0;
#pragma unroll
    for (int j = 0; j < NT / 32; j++) {
      int n = wn * (NT / 2) + j * 16 + cn;
#pragma unroll
      for (int r = 0; r < 4; r++)
        part[((size_t)slice * NTOK + m + r) * NT + n] = acc[i][j][r];
    }
  }
}

// ---------------------------------------------------------------------------
// out[i] = tanh(sum over NSLICE partials).  One float4 per thread.
__global__ __launch_bounds__(256) void k_reduce_tanh(
    const float* __restrict__ part, float* __restrict__ out, int n4) {
  int i = blockIdx.x * 256 + threadIdx.x;
  f32x4 s = (f32x4){0.f, 0.f, 0.f, 0.f};
#pragma unroll 8
  for (int sl = 0; sl < NSLICE; sl++)
    s += *(const f32x4*)&part[(size_t)sl * n4 * 4 + i * 4];
  float4 o;
  o.x = tanhf(s[0]); o.y = tanhf(s[1]); o.z = tanhf(s[2]); o.w = tanhf(s[3]);
  ((float4*)out)[i] = o;
}

// ---------------------------------------------------------------------------
// m_r = mm @ maa_w2[r]; fuse xr/xk/xv (bf16) and xwb (bf16) outputs.
// grid: (NTOK/8, Cz/256), block 256.
__global__ __launch_bounds__(256) void k_mproj(
    const float* __restrict__ mm, const float* __restrict__ w2,
    const float* __restrict__ x, const float* __restrict__ dx,
    const float* __restrict__ maa_r, const float* __restrict__ maa_k,
    const float* __restrict__ maa_v, const float* __restrict__ maa_w,
    bf16* __restrict__ pxr, bf16* __restrict__ pxk,
    bf16* __restrict__ pxv, bf16* __restrict__ pxw) {
  __shared__ float sM[8][128];
  int tid = threadIdx.x;
  int tok0 = blockIdx.x * 8;
  int c = blockIdx.y * 256 + tid;
#pragma unroll
  for (int u = 0; u < 4; u++) {
    int idx = tid + 256 * u;
    sM[idx >> 7][idx & 127] = mm[(size_t)tok0 * 128 + idx];
  }
  __syncthreads();
  float m_[4][8];
#pragma unroll
  for (int r = 0; r < 4; r++)
#pragma unroll
    for (int t = 0; t < 8; t++) m_[r][t] = 0.f;
#pragma unroll
  for (int r = 0; r < 4; r++) {
#pragma unroll 8
    for (int d = 0; d < 32; d++) {
      float w = w2[(size_t)(r * 32 + d) * Cz + c];
#pragma unroll
      for (int t = 0; t < 8; t++) m_[r][t] += w * sM[t][r * 32 + d];
    }
  }
  float mr = maa_r[c], mk = maa_k[c], mv = maa_v[c], mw = maa_w[c];
#pragma unroll
  for (int t = 0; t < 8; t++) {
    size_t idx = (size_t)(tok0 + t) * Cz + c;
    float xval = x[idx], dval = dx[idx];
    pxr[idx] = __float2bfloat16(xval + dval * (mr + m_[0][t]));
    pxk[idx] = __float2bfloat16(xval + dval * (mk + m_[1][t]));
    pxv[idx] = __float2bfloat16(xval + dval * (mv + m_[2][t]));
    pxw[idx] = __float2bfloat16(xval + dval * (mw + m_[3][t]));
  }
}

// ---------------------------------------------------------------------------
// w_log = max(-exp(td + tw @ td_w2), -5); write wlog (f32) and ksc = 1-exp(wlog)
// grid: (NTOK/8, Cz/256)
__global__ __launch_bounds__(256) void k_tdB(
    const float* __restrict__ tw, const float* __restrict__ w2,
    const float* __restrict__ td, float* __restrict__ wlog,
    float* __restrict__ ksc) {
  __shared__ float sT[8][64];
  int tid = threadIdx.x;
  int tok0 = blockIdx.x * 8;
  int c = blockIdx.y * 256 + tid;
#pragma unroll
  for (int u = 0; u < 2; u++) {
    int idx = tid + 256 * u;
    sT[idx >> 6][idx & 63] = tw[(size_t)tok0 * 64 + idx];
  }
  __syncthreads();
  float acc[8];
#pragma unroll
  for (int t = 0; t < 8; t++) acc[t] = 0.f;
#pragma unroll 8
  for (int d = 0; d < 64; d++) {
    float w = w2[(size_t)d * Cz + c];
#pragma unroll
    for (int t = 0; t < 8; t++) acc[t] += w * sT[t][d];
  }
  float tdc = td[c];
#pragma unroll
  for (int t = 0; t < 8; t++) {
    float wl = -expf(tdc + acc[t]);
    wl = fmaxf(wl, -5.0f);
    size_t idx = (size_t)(tok0 + t) * Cz + c;
    wlog[idx] = wl;
    ksc[idx] = 1.f - expf(wl);
  }
}

// ---------------------------------------------------------------------------
// q/k/v projection: 128x64 tile, grid (32 N-tiles, 8 M-tiles, 3 projs).
__global__ __launch_bounds__(256) void k_gemm_qkv(
    const bf16* __restrict__ xr, const bf16* __restrict__ xk,
    const bf16* __restrict__ xv, const bf16* __restrict__ qwt,
    const bf16* __restrict__ kwt, const bf16* __restrict__ vwt,
    const float* __restrict__ qb, const float* __restrict__ kb,
    const float* __restrict__ vb, const float* __restrict__ kscl,
    float* __restrict__ q, float* __restrict__ k, float* __restrict__ v) {
  const bf16 *A, *W;
  const float* b;
  const float* ks = nullptr;
  float* o;
  float scl = 1.f;
  if (blockIdx.z == 0) {
    A = xr; W = qwt; b = qb; o = q; scl = 0.125f;  // fold Dh^-0.5 into q
  } else if (blockIdx.z == 1) {
    A = xk; W = kwt; b = kb; o = k; ks = kscl;
  } else {
    A = xv; W = vwt; b = vb; o = v;
  }
  f32x4 acc[4][2];
#pragma unroll
  for (int i = 0; i < 4; i++)
#pragma unroll
    for (int j = 0; j < 2; j++) acc[i][j] = (f32x4){0.f, 0.f, 0.f, 0.f};
  gemm_core<128, 64>(A, W, blockIdx.y * 128, blockIdx.x * 64, 0, Cz, acc);
  int lane = threadIdx.x & 63, wave = threadIdx.x >> 6;
  int wm = wave & 1, wn = wave >> 1;
  int r0 = (lane >> 4) * 4, cn = lane & 15;
#pragma unroll
  for (int i = 0; i < 4; i++) {
    int m = blockIdx.y * 128 + wm * 64 + i * 16 + r0;
#pragma unroll
    for (int j = 0; j < 2; j++) {
      int n = blockIdx.x * 64 + wn * 32 + j * 16 + cn;
      float bv = b[n];
#pragma unroll
      for (int r = 0; r < 4; r++) {
        float vv = (acc[i][j][r] + bv) * scl;
        size_t oi = (size_t)(m + r) * Cz + n;
        if (ks) vv *= ks[oi];
        o[oi] = vv;
      }
    }
  }
}

// ---------------------------------------------------------------------------
// Output projection, split-K=2: part[z][1024][2048].  grid (32, 8, 2).
__global__ __launch_bounds__(256) void k_gemm_o_split(
    const bf16* __restrict__ yb, const bf16* __restrict__ owt,
    float* __restrict__ part) {
  int z = blockIdx.z;
  f32x4 acc[4][2];
#pragma unroll
  for (int i = 0; i < 4; i++)
#pragma unroll
    for (int j = 0; j < 2; j++) acc[i][j] = (f32x4){0.f, 0.f, 0.f, 0.f};
  gemm_core<128, 64>(yb, owt, blockIdx.y * 128, blockIdx.x * 64, z * 1024,
                     z * 1024 + 1024, acc);
  int lane = threadIdx.x & 63, wave = threadIdx.x >> 6;
  int wm = wave & 1, wn = wave >> 1;
  int r0 = (lane >> 4) * 4, cn = lane & 15;
  size_t pbase = (size_t)z * NTOK * Cz;
#pragma unroll
  for (int i = 0; i < 4; i++) {
    int m = blockIdx.y * 128 + wm * 64 + i * 16 + r0;
#pragma unroll
    for (int j = 0; j < 2; j++) {
      int n = blockIdx.x * 64 + wn * 32 + j * 16 + cn;
#pragma unroll
      for (int r = 0; r < 4; r++)
        part[pbase + (size_t)(m + r) * Cz + n] = acc[i][j][r];
    }
  }
}

__global__ __launch_bounds__(256) void k_combine_o(
    const float* __restrict__ part, float* __restrict__ out) {
  int i = blockIdx.x * 256 + threadIdx.x;
  f32x4 a = *(const f32x4*)&part[(size_t)i * 4];
  f32x4 b = *(const f32x4*)&part[(size_t)NTOK * Cz + (size_t)i * 4];
  *(f32x4*)&out[(size_t)i * 4] = a + b;
}

// ---------------------------------------------------------------------------
// Chunked GLA pass 1: per (b,h,chunk of 64): cumsum of wlog; emit
// qt = q*exp(cum), kt = k*exp(-cum), kh = k*exp(cumL-cum) (bf16, chunk-major),
// aL[d] = exp(cumL), and U[d][j] = sum_s kh[s][d]*v[s][j].
__global__ __launch_bounds__(256) void k_chunk_prep(
    const float* __restrict__ q, const float* __restrict__ k,
    const float* __restrict__ v, const float* __restrict__ wlog,
    bf16* __restrict__ qt, bf16* __restrict__ kt, bf16* __restrict__ kh,
    float* __restrict__ aL, float* __restrict__ U) {
  __shared__ float sCum[64 * 64];
  __shared__ float sKh[64 * 64];
  __shared__ float sV[64 * 64];
  int tid = threadIdx.x;
  int bhc = blockIdx.x;
  int c = bhc & 7, h = (bhc >> 3) & 31, b = bhc >> 8;
  size_t gbase = ((size_t)(b * Tz) + c * 64) * Cz + h * 64;
  size_t cbase = (size_t)bhc * 4096;

#pragma unroll
  for (int i = 0; i < 4; i++) {
    int i4 = tid + i * 256;           // 1024 float4
    int t = i4 >> 4, dq = i4 & 15;
    size_t g = gbase + (size_t)t * Cz + dq * 4;
    *(float4*)&sCum[t * 64 + dq * 4] = *(const float4*)&wlog[g];
    *(float4*)&sKh[t * 64 + dq * 4] = *(const float4*)&k[g];
    *(float4*)&sV[t * 64 + dq * 4] = *(const float4*)&v[g];
  }
  __syncthreads();
  if (tid < 64) {
    float cum = 0.f;
#pragma unroll
    for (int t = 0; t < 64; t++) {
      cum += sCum[t * 64 + tid];
      sCum[t * 64 + tid] = cum;
    }
  }
  __syncthreads();
#pragma unroll
  for (int i = 0; i < 16; i++) {
    int idx = tid + i * 256;
    int t = idx >> 6, d = idx & 63;
    float cl = sCum[t * 64 + d];
    float cL = sCum[63 * 64 + d];
    float kraw = sKh[t * 64 + d];
    float qv = q[gbase + (size_t)t * Cz + d];
    float khv = kraw * expf(cL - cl);
    qt[cbase + idx] = __float2bfloat16(qv * expf(cl));
    kt[cbase + idx] = __float2bfloat16(kraw * expf(-cl));
    kh[cbase + idx] = __float2bfloat16(khv);
    sKh[t * 64 + d] = khv;
    if (t == 63) aL[(size_t)bhc * 64 + d] = expf(cl);
  }
  __syncthreads();
  int j = tid & 63, dg = tid >> 6;
  float acc[16];
#pragma unroll
  for (int dd = 0; dd < 16; dd++) acc[dd] = 0.f;
  for (int s = 0; s < 64; s++) {
    float vs = sV[s * 64 + j];
#pragma unroll
    for (int dd = 0; dd < 16; dd++)
      acc[dd] += sKh[s * 64 + dg * 16 + dd] * vs;
  }
#pragma unroll
  for (int dd = 0; dd < 16; dd++)
    U[cbase + (size_t)(dg * 16 + dd) * 64 + j] = acc[dd];
}

// ---------------------------------------------------------------------------
// Chunked GLA pass 2 (sequential over 8 chunks): S_{c+1} = diag(aL)*S_c + U_c.
__global__ __launch_bounds__(64) void k_carry(
    const float* __restrict__ aL, const float* __restrict__ U,
    float* __restrict__ Sc) {
  int bh = blockIdx.x >> 2;
  int jg = blockIdx.x & 3;
  int tid = threadIdx.x;
  int jj = tid & 15, dg = tid >> 4;
  int j = jg * 16 + jj;
  float S[16];
#pragma unroll
  for (int dd = 0; dd < 16; dd++) S[dd] = 0.f;
  for (int c = 0; c < NCH; c++) {
    int bhc = bh * NCH + c;
    size_t base = (size_t)bhc * 4096;
#pragma unroll
    for (int dd = 0; dd < 16; dd++) {
      int d = dg * 16 + dd;
      Sc[base + (size_t)d * 64 + j] = S[dd];
      S[dd] = S[dd] * aL[(size_t)bhc * 64 + d] + U[base + (size_t)d * 64 + j];
    }
  }
}

// ---------------------------------------------------------------------------
// Chunked GLA pass 3: o = mask(qt @ kt^T) @ V + qt @ S_c.  512 blocks.
__global__ __launch_bounds__(256) void k_chunk_out(
    const bf16* __restrict__ qt, const bf16* __restrict__ kt,
    const float* __restrict__ v, const float* __restrict__ Sc,
    float* __restrict__ y) {
  __shared__ float sQ[64 * 65];
  __shared__ float sKS[64 * 65];  // k-tilde (stride 65), later S (stride 64)
  __shared__ float sP[64 * 65];
  __shared__ float sV[64 * 64];
  int tid = threadIdx.x;
  int bhc = blockIdx.x;
  int c = bhc & 7, h = (bhc >> 3) & 31, b = bhc >> 8;
  size_t gbase = ((size_t)(b * Tz) + c * 64) * Cz + h * 64;
  size_t cbase = (size_t)bhc * 4096;

#pragma unroll
  for (int i = 0; i < 4; i++) {
    int i4 = tid + i * 256;  // 1024 quads
    int t = i4 >> 4, dq = i4 & 15;
    ushort4 qu = *(const ushort4*)&qt[cbase + i4 * 4];
    ushort4 ku = *(const ushort4*)&kt[cbase + i4 * 4];
    float* dstq = &sQ[t * 65 + dq * 4];
    float* dstk = &sKS[t * 65 + dq * 4];
    unsigned int uq[4] = {qu.x, qu.y, qu.z, qu.w};
    unsigned int uk[4] = {ku.x, ku.y, ku.z, ku.w};
#pragma unroll
    for (int e = 0; e < 4; e++) {
      unsigned int bq = uq[e] << 16;
      unsigned int bk = uk[e] << 16;
      dstq[e] = __builtin_bit_cast(float, bq);
      dstk[e] = __builtin_bit_cast(float, bk);
    }
  }
  __syncthreads();
  int tg = tid & 15, sg = tid >> 4;
  float p[4][4];
#pragma unroll
  for (int i = 0; i < 4; i++)
#pragma unroll
    for (int jx = 0; jx < 4; jx++) p[i][jx] = 0.f;
  for (int d = 0; d < 64; d++) {
    float qv[4], kv[4];
#pragma unroll
    for (int i = 0; i < 4; i++) qv[i] = sQ[(tg * 4 + i) * 65 + d];
#pragma unroll
    for (int jx = 0; jx < 4; jx++) kv[jx] = sKS[(sg * 4 + jx) * 65 + d];
#pragma unroll
    for (int i = 0; i < 4; i++)
#pragma unroll
      for (int jx = 0; jx < 4; jx++) p[i][jx] += qv[i] * kv[jx];
  }
#pragma unroll
  for (int i = 0; i < 4; i++) {
    int t = tg * 4 + i;
#pragma unroll
    for (int jx = 0; jx < 4; jx++) {
      int s = sg * 4 + jx;
      sP[t * 65 + s] = (s <= t) ? p[i][jx] : 0.f;
    }
  }
  __syncthreads();
#pragma unroll
  for (int i = 0; i < 4; i++) {
    int i4 = tid + i * 256;
    int t = i4 >> 4, dq = i4 & 15;
    *(float4*)&sKS[t * 64 + dq * 4] = *(const float4*)&Sc[cbase + i4 * 4];
    *(float4*)&sV[t * 64 + dq * 4] =
        *(const float4*)&v[gbase + (size_t)t * Cz + dq * 4];
  }
  __syncthreads();
  f32x4 o[4];
#pragma unroll
  for (int i = 0; i < 4; i++) o[i] = (f32x4){0.f, 0.f, 0.f, 0.f};
  for (int s = 0; s < 64; s++) {
    f32x4 vv = *(const f32x4*)&sV[s * 64 + sg * 4];
#pragma unroll
    for (int i = 0; i < 4; i++) {
      float pv = sP[(tg * 4 + i) * 65 + s];
      o[i] += pv * vv;
    }
  }
  for (int d = 0; d < 64; d++) {
    f32x4 sv = *(const f32x4*)&sKS[d * 64 + sg * 4];
#pragma unroll
    for (int i = 0; i < 4; i++) {
      float qv = sQ[(tg * 4 + i) * 65 + d];
      o[i] += qv * sv;
    }
  }
#pragma unroll
  for (int i = 0; i < 4; i++) {
    int t = tg * 4 + i;
    *(f32x4*)&y[gbase + (size_t)t * Cz + sg * 4] = o[i];
  }
}

// ---------------------------------------------------------------------------
// LayerNorm over C, write bf16
__global__ __launch_bounds__(256) void k_ln(
    const float* __restrict__ y, const float* __restrict__ lg,
    const float* __restrict__ lb, bf16* __restrict__ yb) {
  __shared__ float red[8];
  int t = blockIdx.x;
  int tid = threadIdx.x;
  const float4* y4 = (const float4*)(y + (size_t)t * Cz);
  float4 vals[2];
  float s = 0.f, s2 = 0.f;
#pragma unroll
  for (int u = 0; u < 2; u++) {
    float4 a = y4[tid + 256 * u];
    vals[u] = a;
    s += a.x + a.y + a.z + a.w;
    s2 += a.x * a.x + a.y * a.y + a.z * a.z + a.w * a.w;
  }
#pragma unroll
  for (int off = 32; off > 0; off >>= 1) {
    s += __shfl_down(s, off);
    s2 += __shfl_down(s2, off);
  }
  if ((tid & 63) == 0) {
    red[(tid >> 6) * 2] = s;
    red[(tid >> 6) * 2 + 1] = s2;
  }
  __syncthreads();
  float ts = red[0] + red[2] + red[4] + red[6];
  float ts2 = red[1] + red[3] + red[5] + red[7];
  float mu = ts / (float)Cz;
  float var = ts2 / (float)Cz - mu * mu;
  float inv = rsqrtf(var + 1e-5f);
  bf16* outp = yb + (size_t)t * Cz;
#pragma unroll
  for (int u = 0; u < 2; u++) {
    int c0 = (tid + 256 * u) * 4;
    float4 a = vals[u];
    outp[c0 + 0] = __float2bfloat16((a.x - mu) * inv * lg[c0 + 0] + lb[c0 + 0]);
    outp[c0 + 1] = __float2bfloat16((a.y - mu) * inv * lg[c0 + 1] + lb[c0 + 1]);
    outp[c0 + 2] = __float2bfloat16((a.z - mu) * inv * lg[c0 + 2] + lb[c0 + 2]);
    outp[c0 + 3] = __float2bfloat16((a.w - mu) * inv * lg[c0 + 3] + lb[c0 + 3]);
  }
}

// ---------------------------------------------------------------------------
extern "C" void kernel_launch(void* const* d_in, const int* in_sizes, int n_in,
                              void* d_out, int out_size, void* d_ws,
                              size_t ws_size, hipStream_t stream) {
  const float* x      = (const float*)d_in[0];
  const float* maa_x  = (const float*)d_in[1];
  const float* maa_r  = (const float*)d_in[2];
  const float* maa_k  = (const float*)d_in[3];
  const float* maa_v  = (const float*)d_in[4];
  const float* maa_w  = (const float*)d_in[5];
  const float* maa_w1 = (const float*)d_in[6];
  const float* maa_w2 = (const float*)d_in[7];
  const float* tdcay  = (const float*)d_in[8];
  const float* td_w1  = (const float*)d_in[9];
  const float* td_w2  = (const float*)d_in[10];
  const float* q_w    = (const float*)d_in[11];
  const float* q_b    = (const float*)d_in[12];
  const float* k_w    = (const float*)d_in[13];
  const float* k_b    = (const float*)d_in[14];
  const float* v_w    = (const float*)d_in[15];
  const float* v_b    = (const float*)d_in[16];
  const float* ln_g   = (const float*)d_in[17];
  const float* ln_b   = (const float*)d_in[18];
  const float* o_w    = (const float*)d_in[19];
  float* out = (float*)d_out;

  char* p = (char*)d_ws;
  auto alloc = [&](size_t bytes) {
    char* r = p;
    p += (bytes + 255) & ~(size_t)255;
    return r;
  };
  const size_t WB = (size_t)Cz * Cz * sizeof(bf16);    // 8 MB
  const size_t AF = (size_t)NTOK * Cz * sizeof(float); // 8 MB
  const size_t AB = (size_t)NTOK * Cz * sizeof(bf16);  // 4 MB

  bf16* qwt = (bf16*)alloc(WB);
  bf16* kwt = (bf16*)alloc(WB);
  bf16* vwt = (bf16*)alloc(WB);
  bf16* owt = (bf16*)alloc(WB);
  float* dx   = (float*)alloc(AF);
  char* xslot = (char*)alloc(AF);   // 8 MB multi-use
  float* mm  = (float*)alloc((size_t)NTOK * 128 * sizeof(float));
  bf16* xr = (bf16*)alloc(AB);
  bf16* xk = (bf16*)alloc(AB);
  bf16* xv = (bf16*)alloc(AB);
  char* xwslot = (char*)alloc(AF);  // 8 MB multi-use
  float* tw = (float*)alloc((size_t)NTOK * 64 * sizeof(float));
  float* wlog = (float*)alloc(AF);
  float* kscl = (float*)alloc(AF);
  float* qk2 = (float*)alloc(2 * AF);  // q and k, contiguous 16 MB
  float* v = (float*)alloc(AF);
  float* y = (float*)alloc(AF);
  bf16* yb = (bf16*)alloc(AB);

  float* q = qk2;
  float* k = qk2 + (size_t)NTOK * Cz;

  // xslot: [0,4M) xxxb (steps 2-3) then qt (step 8+);
  //        [4M,4.5M) w1t (steps 1b-3); [4.5M,4.75M) tdw1t (steps 1b-5);
  //        [4M,8M) kt (step 8+).
  bf16* xxxb = (bf16*)xslot;
  bf16* w1t = (bf16*)(xslot + 4 * 1024 * 1024);
  bf16* tdw1t = (bf16*)(xslot + 4 * 1024 * 1024 + 512 * 1024);
  bf16* qt = (bf16*)xslot;
  bf16* kt = (bf16*)(xslot + 4 * 1024 * 1024);
  // xwslot: [0,4M) xwb (steps 4-5), then U full 8 MB (step 8+).
  bf16* xwb = (bf16*)xwslot;
  float* U = (float*)xwslot;
  // mm partials (16 MB): qk2 region, dead until step 7.
  float* mm_part = qk2;
  // tw partials (8 MB): v slot, dead until step 7.
  float* tw_part = v;
  // o partials (16 MB): wlog+kscl contiguous, dead after step 8a.
  float* o_part = wlog;
  float* Scar = q;        // q dead after k_chunk_prep
  bf16* kh = (bf16*)dx;   // dx dead after k_mproj
  float* aLbuf = mm;      // mm dead after k_mproj

  // 1. weight transpose+convert
  k_transpose<<<dim3(64, 64, 4), dim3(32, 8), 0, stream>>>(
      q_w, k_w, v_w, o_w, qwt, kwt, vwt, owt);
  k_transpose_small<<<dim3(64, 6), dim3(32, 8), 0, stream>>>(
      maa_w1, td_w1, w1t, tdw1t);
  // 2. token shift
  k_prep<<<2048, 256, 0, stream>>>(x, maa_x, dx, xxxb);
  // 3. mix LoRA stage 1: split-K MFMA + reduce/tanh
  k_lora_gemm<128><<<dim3(8, NSLICE), 256, 0, stream>>>(xxxb, w1t, mm_part);
  k_reduce_tanh<<<128, 256, 0, stream>>>(mm_part, mm, NTOK * 128 / 4);
  // 4. mix LoRA stage 2 + fused xr/xk/xv/xwb
  k_mproj<<<dim3(128, 8), 256, 0, stream>>>(mm, maa_w2, x, dx, maa_r, maa_k,
                                            maa_v, maa_w, xr, xk, xv, xwb);
  // 5. decay LoRA stage 1: split-K MFMA + reduce/tanh
  k_lora_gemm<64><<<dim3(8, NSLICE), 256, 0, stream>>>(xwb, tdw1t, tw_part);
  k_reduce_tanh<<<64, 256, 0, stream>>>(tw_part, tw, NTOK * 64 / 4);
  // 6. decay LoRA stage 2
  k_tdB<<<dim3(128, 8), 256, 0, stream>>>(tw, td_w2, tdcay, wlog, kscl);
  // 7. q,k,v projections (k scaled by 1-exp(wlog), q scaled by Dh^-0.5)
  k_gemm_qkv<<<dim3(32, 8, 3), 256, 0, stream>>>(
      xr, xk, xv, qwt, kwt, vwt, q_b, k_b, v_b, kscl, q, k, v);
  // 8. chunked GLA
  k_chunk_prep<<<512, 256, 0, stream>>>(q, k, v, wlog, qt, kt, kh, aLbuf, U);
  k_carry<<<256, 64, 0, stream>>>(aLbuf, U, Scar);
  k_chunk_out<<<512, 256, 0, stream>>>(qt, kt, v, Scar, y);
  // 9. LayerNorm -> bf16
  k_ln<<<NTOK, 256, 0, stream>>>(y, ln_g, ln_b, yb);
  // 10. output projection (split-K=2 + combine)
  k_gemm_o_split<<<dim3(32, 8, 2), 256, 0, stream>>>(yb, owt, o_part);
  k_combine_o<<<2048, 256, 0, stream>>>(o_part, out);
}

// Round 6
// 326.458 us; speedup vs baseline: 1.8106x; 1.0889x over previous
//
#include <hip/hip_runtime.h>
#include <hip/hip_bf16.h>
#include <math.h>

// Problem constants
#define Bz 2
#define Tz 512
#define Cz 2048
#define Hh 32
#define DH 64
#define NTOK (Bz * Tz)   // 1024
#define NCH 8            // chunks per sequence (Tz/64)
#define NSLICE 32        // split-K slices for LoRA GEMMs (K-slice = 64)

typedef __hip_bfloat16 bf16;
typedef __attribute__((ext_vector_type(8))) short short8;
typedef __attribute__((ext_vector_type(4))) float f32x4;

// ---------------------------------------------------------------------------
__device__ __forceinline__ void load_lds16(const void* g, void* l) {
  __builtin_amdgcn_global_load_lds(
      (const __attribute__((address_space(1))) unsigned int*)g,
      (__attribute__((address_space(3))) unsigned int*)l,
      16, 0, 0);
}

__device__ __forceinline__ f32x4 bf4_to_f32(ushort4 u) {
  f32x4 r;
  r[0] = __builtin_bit_cast(float, (unsigned)u.x << 16);
  r[1] = __builtin_bit_cast(float, (unsigned)u.y << 16);
  r[2] = __builtin_bit_cast(float, (unsigned)u.z << 16);
  r[3] = __builtin_bit_cast(float, (unsigned)u.w << 16);
  return r;
}

// ---------------------------------------------------------------------------
// Shared MFMA GEMM core: A[M][K=2048] @ Bt[N][K]^T over k in [kBeg,kEnd).
// 4 waves arranged 2x2; wave tile (MT/2)x(NT/2); 16x16x32 bf16 MFMA.
template <int MT, int NT>
__device__ __forceinline__ void gemm_core(
    const bf16* __restrict__ A, const bf16* __restrict__ Bt,
    int M0, int N0, int kBeg, int kEnd,
    f32x4 (&acc)[MT / 32][NT / 32]) {
  constexpr int AI = MT / 32, BJ = NT / 32;
  constexpr int TSA = MT / 16, TS = (MT + NT) / 16;
  static_assert(TS % 4 == 0, "strips must divide among 4 waves");
  __shared__ alignas(16) bf16 As[MT * 32];
  __shared__ alignas(16) bf16 Bs[NT * 32];
  int tid = threadIdx.x, lane = tid & 63, wave = tid >> 6;
  int wm = wave & 1, wn = wave >> 1;
  int srow = lane >> 2, scol = (lane & 3) * 8;
  int fr = lane & 15, fk = (lane >> 4) * 8;
  const bf16* rA = As + (wm * (MT / 2) + fr) * 32 + fk;
  const bf16* rB = Bs + (wn * (NT / 2) + fr) * 32 + fk;

  for (int k0 = kBeg; k0 < kEnd; k0 += 32) {
#pragma unroll
    for (int s = wave; s < TS; s += 4) {
      if (s < TSA)
        load_lds16(A + (size_t)(M0 + s * 16 + srow) * Cz + k0 + scol,
                   As + s * 16 * 32);
      else
        load_lds16(Bt + (size_t)(N0 + (s - TSA) * 16 + srow) * Cz + k0 + scol,
                   Bs + (s - TSA) * 16 * 32);
    }
    __syncthreads();
    short8 af[AI], bf[BJ];
#pragma unroll
    for (int i = 0; i < AI; i++) af[i] = *(const short8*)(rA + i * 16 * 32);
#pragma unroll
    for (int j = 0; j < BJ; j++) bf[j] = *(const short8*)(rB + j * 16 * 32);
#pragma unroll
    for (int i = 0; i < AI; i++)
#pragma unroll
      for (int j = 0; j < BJ; j++)
        acc[i][j] = __builtin_amdgcn_mfma_f32_16x16x32_bf16(af[i], bf[j],
                                                            acc[i][j], 0, 0, 0);
    __syncthreads();
  }
}

// ---------------------------------------------------------------------------
// Fused setup: blocks [0,16384): big weight transposes; [16384,16768): LoRA
// weight transposes; [16768,18816): token-shift prep. Block = (32,8).
__global__ __launch_bounds__(256) void k_setup(
    const float* __restrict__ qw, const float* __restrict__ kw,
    const float* __restrict__ vw, const float* __restrict__ ow,
    const float* __restrict__ w1, const float* __restrict__ tdw1,
    const float* __restrict__ x, const float* __restrict__ maa_x,
    bf16* __restrict__ qwt, bf16* __restrict__ kwt, bf16* __restrict__ vwt,
    bf16* __restrict__ owt, bf16* __restrict__ w1t, bf16* __restrict__ tdw1t,
    float* __restrict__ dx, bf16* __restrict__ xxxb) {
  __shared__ float tile[32][33];
  int bid = blockIdx.x;
  int tx = threadIdx.x, ty = threadIdx.y;
  if (bid < 16384) {
    int w = bid >> 12, r = bid & 4095;
    const float* W = w == 0 ? qw : w == 1 ? kw : w == 2 ? vw : ow;
    bf16* O = w == 0 ? qwt : w == 1 ? kwt : w == 2 ? vwt : owt;
    int bx = (r & 63) * 32, by = (r >> 6) * 32;
#pragma unroll
    for (int i = 0; i < 4; i++)
      tile[ty + 8 * i][tx] = W[(size_t)(by + ty + 8 * i) * Cz + bx + tx];
    __syncthreads();
#pragma unroll
    for (int i = 0; i < 4; i++)
      O[(size_t)(bx + ty + 8 * i) * Cz + by + tx] =
          __float2bfloat16(tile[tx][ty + 8 * i]);
  } else if (bid < 16768) {
    int r = bid - 16384;
    int z = r >> 6;           // 0..5
    int bk = (r & 63) * 32;
    const float* W;
    bf16* O;
    int N, bn;
    if (z < 4) { W = w1; O = w1t; N = 128; bn = z * 32; }
    else       { W = tdw1; O = tdw1t; N = 64; bn = (z - 4) * 32; }
#pragma unroll
    for (int i = 0; i < 4; i++)
      tile[ty + 8 * i][tx] = W[(size_t)(bk + ty + 8 * i) * N + bn + tx];
    __syncthreads();
#pragma unroll
    for (int i = 0; i < 4; i++)
      O[(size_t)(bn + ty + 8 * i) * Cz + bk + tx] =
          __float2bfloat16(tile[tx][ty + 8 * i]);
  } else {
    int r = bid - 16768;
    int tid = ty * 32 + tx;
    int i4 = r * 256 + tid;                 // over 262144 float4
    int row = i4 >> 9, t = row & (Tz - 1), c4 = i4 & 511;
    const float4* x4 = (const float4*)x;
    float4 xv = x4[i4];
    float4 xp = make_float4(0.f, 0.f, 0.f, 0.f);
    if (t != 0) xp = x4[i4 - 512];
    float4 mx = ((const float4*)maa_x)[c4];
    float4 d, xx;
    d.x = xp.x - xv.x; d.y = xp.y - xv.y; d.z = xp.z - xv.z; d.w = xp.w - xv.w;
    xx.x = xv.x + d.x * mx.x; xx.y = xv.y + d.y * mx.y;
    xx.z = xv.z + d.z * mx.z; xx.w = xv.w + d.w * mx.w;
    ((float4*)dx)[i4] = d;
    ushort4 u;
    u.x = __builtin_bit_cast(unsigned short, __float2bfloat16(xx.x));
    u.y = __builtin_bit_cast(unsigned short, __float2bfloat16(xx.y));
    u.z = __builtin_bit_cast(unsigned short, __float2bfloat16(xx.z));
    u.w = __builtin_bit_cast(unsigned short, __float2bfloat16(xx.w));
    ((ushort4*)xxxb)[i4] = u;
  }
}

// ---------------------------------------------------------------------------
// Split-K LoRA GEMM: part[slice][1024][NT] = A @ Bt^T over K-slice of 64.
template <int NT>
__global__ __launch_bounds__(256) void k_lora_gemm(
    const bf16* __restrict__ A, const bf16* __restrict__ Bt,
    float* __restrict__ part) {
  constexpr int KS = Cz / NSLICE;  // 64
  f32x4 acc[4][NT / 32];
#pragma unroll
  for (int i = 0; i < 4; i++)
#pragma unroll
    for (int j = 0; j < NT / 32; j++) acc[i][j] = (f32x4){0.f, 0.f, 0.f, 0.f};
  int bM = blockIdx.x, slice = blockIdx.y;
  gemm_core<128, NT>(A, Bt, bM * 128, 0, slice * KS, slice * KS + KS, acc);
  int lane = threadIdx.x & 63, wave = threadIdx.x >> 6;
  int wm = wave & 1, wn = wave >> 1;
  int r0 = (lane >> 4) * 4, cn = lane & 15;
#pragma unroll
  for (int i = 0; i < 4; i++) {
    int m = bM * 128 + wm * 64 + i * 16 + r0;
#pragma unroll
    for (int j = 0; j < NT / 32; j++) {
      int n = wn * (NT / 2) + j * 16 + cn;
#pragma unroll
      for (int r = 0; r < 4; r++)
        part[((size_t)slice * NTOK + m + r) * NT + n] = acc[i][j][r];
    }
  }
}

// ---------------------------------------------------------------------------
__global__ __launch_bounds__(256) void k_reduce_tanh(
    const float* __restrict__ part, float* __restrict__ out, int n4) {
  int i = blockIdx.x * 256 + threadIdx.x;
  f32x4 s = (f32x4){0.f, 0.f, 0.f, 0.f};
#pragma unroll 8
  for (int sl = 0; sl < NSLICE; sl++)
    s += *(const f32x4*)&part[(size_t)sl * n4 * 4 + i * 4];
  float4 o;
  o.x = tanhf(s[0]); o.y = tanhf(s[1]); o.z = tanhf(s[2]); o.w = tanhf(s[3]);
  ((float4*)out)[i] = o;
}

// ---------------------------------------------------------------------------
// m_r = mm @ maa_w2[r]; fuse xr/xk/xv/xwb (bf16) outputs.
__global__ __launch_bounds__(256) void k_mproj(
    const float* __restrict__ mm, const float* __restrict__ w2,
    const float* __restrict__ x, const float* __restrict__ dx,
    const float* __restrict__ maa_r, const float* __restrict__ maa_k,
    const float* __restrict__ maa_v, const float* __restrict__ maa_w,
    bf16* __restrict__ pxr, bf16* __restrict__ pxk,
    bf16* __restrict__ pxv, bf16* __restrict__ pxw) {
  __shared__ float sM[8][128];
  int tid = threadIdx.x;
  int tok0 = blockIdx.x * 8;
  int c = blockIdx.y * 256 + tid;
#pragma unroll
  for (int u = 0; u < 4; u++) {
    int idx = tid + 256 * u;
    sM[idx >> 7][idx & 127] = mm[(size_t)tok0 * 128 + idx];
  }
  __syncthreads();
  float m_[4][8];
#pragma unroll
  for (int r = 0; r < 4; r++)
#pragma unroll
    for (int t = 0; t < 8; t++) m_[r][t] = 0.f;
#pragma unroll
  for (int r = 0; r < 4; r++) {
#pragma unroll 8
    for (int d = 0; d < 32; d++) {
      float w = w2[(size_t)(r * 32 + d) * Cz + c];
#pragma unroll
      for (int t = 0; t < 8; t++) m_[r][t] += w * sM[t][r * 32 + d];
    }
  }
  float mr = maa_r[c], mk = maa_k[c], mv = maa_v[c], mw = maa_w[c];
#pragma unroll
  for (int t = 0; t < 8; t++) {
    size_t idx = (size_t)(tok0 + t) * Cz + c;
    float xval = x[idx], dval = dx[idx];
    pxr[idx] = __float2bfloat16(xval + dval * (mr + m_[0][t]));
    pxk[idx] = __float2bfloat16(xval + dval * (mk + m_[1][t]));
    pxv[idx] = __float2bfloat16(xval + dval * (mv + m_[2][t]));
    pxw[idx] = __float2bfloat16(xval + dval * (mw + m_[3][t]));
  }
}

// ---------------------------------------------------------------------------
// wlog = max(-exp(td + tw @ td_w2), -5).  grid: (NTOK/8, Cz/256)
__global__ __launch_bounds__(256) void k_tdB(
    const float* __restrict__ tw, const float* __restrict__ w2,
    const float* __restrict__ td, float* __restrict__ wlog) {
  __shared__ float sT[8][64];
  int tid = threadIdx.x;
  int tok0 = blockIdx.x * 8;
  int c = blockIdx.y * 256 + tid;
#pragma unroll
  for (int u = 0; u < 2; u++) {
    int idx = tid + 256 * u;
    sT[idx >> 6][idx & 63] = tw[(size_t)tok0 * 64 + idx];
  }
  __syncthreads();
  float acc[8];
#pragma unroll
  for (int t = 0; t < 8; t++) acc[t] = 0.f;
#pragma unroll 8
  for (int d = 0; d < 64; d++) {
    float w = w2[(size_t)d * Cz + c];
#pragma unroll
    for (int t = 0; t < 8; t++) acc[t] += w * sT[t][d];
  }
  float tdc = td[c];
#pragma unroll
  for (int t = 0; t < 8; t++) {
    float wl = -expf(tdc + acc[t]);
    wlog[(size_t)(tok0 + t) * Cz + c] = fmaxf(wl, -5.0f);
  }
}

// ---------------------------------------------------------------------------
// q/k/v projections, 128x128 tile, split-K=2, bf16 partials.
// grid (16 N-tiles, 8 M-tiles, 6 = proj*2+slice).
__global__ __launch_bounds__(256) void k_gemm_qkv_split(
    const bf16* __restrict__ xr, const bf16* __restrict__ xk,
    const bf16* __restrict__ xv, const bf16* __restrict__ qwt,
    const bf16* __restrict__ kwt, const bf16* __restrict__ vwt,
    bf16* __restrict__ part) {
  int z = blockIdx.z, proj = z >> 1, slice = z & 1;
  const bf16* A = proj == 0 ? xr : proj == 1 ? xk : xv;
  const bf16* W = proj == 0 ? qwt : proj == 1 ? kwt : vwt;
  f32x4 acc[4][4];
#pragma unroll
  for (int i = 0; i < 4; i++)
#pragma unroll
    for (int j = 0; j < 4; j++) acc[i][j] = (f32x4){0.f, 0.f, 0.f, 0.f};
  gemm_core<128, 128>(A, W, blockIdx.y * 128, blockIdx.x * 128, slice * 1024,
                      slice * 1024 + 1024, acc);
  int lane = threadIdx.x & 63, wave = threadIdx.x >> 6;
  int wm = wave & 1, wn = wave >> 1;
  int r0 = (lane >> 4) * 4, cn = lane & 15;
  bf16* dst = part + (size_t)z * NTOK * Cz;
#pragma unroll
  for (int i = 0; i < 4; i++) {
    int m = blockIdx.y * 128 + wm * 64 + i * 16 + r0;
#pragma unroll
    for (int j = 0; j < 4; j++) {
      int n = blockIdx.x * 128 + wn * 64 + j * 16 + cn;
#pragma unroll
      for (int r = 0; r < 4; r++)
        dst[(size_t)(m + r) * Cz + n] = __float2bfloat16(acc[i][j][r]);
    }
  }
}

// Combine qkv partials + bias (+ q scale). 2048 blocks.
__global__ __launch_bounds__(256) void k_combine_qkv(
    const bf16* __restrict__ part, const float* __restrict__ qb,
    const float* __restrict__ kb, const float* __restrict__ vb,
    float* __restrict__ q, float* __restrict__ k, float* __restrict__ v) {
  int i4 = blockIdx.x * 256 + threadIdx.x;
  int n4 = i4 & 511;
  const size_t P = (size_t)NTOK * Cz;
  const ushort4* pp = (const ushort4*)part;
  const size_t P4 = P / 4;
  float4 b;
  f32x4 s;
  s = bf4_to_f32(pp[i4]) + bf4_to_f32(pp[P4 + i4]);
  b = ((const float4*)qb)[n4];
  s = (s + (f32x4){b.x, b.y, b.z, b.w}) * 0.125f;
  *(f32x4*)&q[(size_t)i4 * 4] = s;
  s = bf4_to_f32(pp[2 * P4 + i4]) + bf4_to_f32(pp[3 * P4 + i4]);
  b = ((const float4*)kb)[n4];
  s = s + (f32x4){b.x, b.y, b.z, b.w};
  *(f32x4*)&k[(size_t)i4 * 4] = s;
  s = bf4_to_f32(pp[4 * P4 + i4]) + bf4_to_f32(pp[5 * P4 + i4]);
  b = ((const float4*)vb)[n4];
  s = s + (f32x4){b.x, b.y, b.z, b.w};
  *(f32x4*)&v[(size_t)i4 * 4] = s;
}

// ---------------------------------------------------------------------------
// Output projection, 128x128 tile, split-K=4, bf16 partials. grid (16,8,4).
__global__ __launch_bounds__(256) void k_gemm_o_split(
    const bf16* __restrict__ yb, const bf16* __restrict__ owt,
    bf16* __restrict__ part) {
  int z = blockIdx.z;
  f32x4 acc[4][4];
#pragma unroll
  for (int i = 0; i < 4; i++)
#pragma unroll
    for (int j = 0; j < 4; j++) acc[i][j] = (f32x4){0.f, 0.f, 0.f, 0.f};
  gemm_core<128, 128>(yb, owt, blockIdx.y * 128, blockIdx.x * 128, z * 512,
                      z * 512 + 512, acc);
  int lane = threadIdx.x & 63, wave = threadIdx.x >> 6;
  int wm = wave & 1, wn = wave >> 1;
  int r0 = (lane >> 4) * 4, cn = lane & 15;
  bf16* dst = part + (size_t)z * NTOK * Cz;
#pragma unroll
  for (int i = 0; i < 4; i++) {
    int m = blockIdx.y * 128 + wm * 64 + i * 16 + r0;
#pragma unroll
    for (int j = 0; j < 4; j++) {
      int n = blockIdx.x * 128 + wn * 64 + j * 16 + cn;
#pragma unroll
      for (int r = 0; r < 4; r++)
        dst[(size_t)(m + r) * Cz + n] = __float2bfloat16(acc[i][j][r]);
    }
  }
}

__global__ __launch_bounds__(256) void k_combine_o(
    const bf16* __restrict__ part, float* __restrict__ out) {
  int i4 = blockIdx.x * 256 + threadIdx.x;
  const size_t P4 = (size_t)NTOK * Cz / 4;
  const ushort4* pp = (const ushort4*)part;
  f32x4 s = bf4_to_f32(pp[i4]) + bf4_to_f32(pp[P4 + i4]) +
            bf4_to_f32(pp[2 * P4 + i4]) + bf4_to_f32(pp[3 * P4 + i4]);
  *(f32x4*)&out[(size_t)i4 * 4] = s;
}

// ---------------------------------------------------------------------------
// Chunked GLA pass 1: applies k-scale (1-exp(wlog)) inline; cumsum of wlog;
// emit qt=q*exp(cum), kt=ks*exp(-cum) (bf16), aL=exp(cumL), U = Kh^T V.
__global__ __launch_bounds__(256) void k_chunk_prep(
    const float* __restrict__ q, const float* __restrict__ k,
    const float* __restrict__ v, const float* __restrict__ wlog,
    bf16* __restrict__ qt, bf16* __restrict__ kt,
    float* __restrict__ aL, float* __restrict__ U) {
  __shared__ float sCum[64 * 64];
  __shared__ float sKh[64 * 64];
  __shared__ float sV[64 * 64];
  int tid = threadIdx.x;
  int bhc = blockIdx.x;
  int c = bhc & 7, h = (bhc >> 3) & 31, b = bhc >> 8;
  size_t gbase = ((size_t)(b * Tz) + c * 64) * Cz + h * 64;
  size_t cbase = (size_t)bhc * 4096;

#pragma unroll
  for (int i = 0; i < 4; i++) {
    int i4 = tid + i * 256;
    int t = i4 >> 4, dq = i4 & 15;
    size_t g = gbase + (size_t)t * Cz + dq * 4;
    *(float4*)&sCum[t * 64 + dq * 4] = *(const float4*)&wlog[g];
    *(float4*)&sKh[t * 64 + dq * 4] = *(const float4*)&k[g];
    *(float4*)&sV[t * 64 + dq * 4] = *(const float4*)&v[g];
  }
  __syncthreads();
  // scale k by (1 - exp(wlog)) before cumsum overwrites sCum
#pragma unroll
  for (int i = 0; i < 16; i++) {
    int idx = tid + i * 256;
    sKh[idx] *= (1.f - expf(sCum[idx]));
  }
  __syncthreads();
  if (tid < 64) {
    float cum = 0.f;
#pragma unroll
    for (int t = 0; t < 64; t++) {
      cum += sCum[t * 64 + tid];
      sCum[t * 64 + tid] = cum;
    }
  }
  __syncthreads();
#pragma unroll
  for (int i = 0; i < 16; i++) {
    int idx = tid + i * 256;
    int t = idx >> 6, d = idx & 63;
    float cl = sCum[t * 64 + d];
    float cL = sCum[63 * 64 + d];
    float kraw = sKh[t * 64 + d];
    float qv = q[gbase + (size_t)t * Cz + d];
    float khv = kraw * expf(cL - cl);
    qt[cbase + idx] = __float2bfloat16(qv * expf(cl));
    kt[cbase + idx] = __float2bfloat16(kraw * expf(-cl));
    sKh[t * 64 + d] = khv;
    if (t == 63) aL[(size_t)bhc * 64 + d] = expf(cl);
  }
  __syncthreads();
  int j = tid & 63, dg = tid >> 6;
  float acc[16];
#pragma unroll
  for (int dd = 0; dd < 16; dd++) acc[dd] = 0.f;
  for (int s = 0; s < 64; s++) {
    float vs = sV[s * 64 + j];
#pragma unroll
    for (int dd = 0; dd < 16; dd++)
      acc[dd] += sKh[s * 64 + dg * 16 + dd] * vs;
  }
#pragma unroll
  for (int dd = 0; dd < 16; dd++)
    U[cbase + (size_t)(dg * 16 + dd) * 64 + j] = acc[dd];
}

// ---------------------------------------------------------------------------
// Chunked GLA pass 2 (carry fused): block (b,h,c) replays S = S*aL + U over
// chunks 0..c-1, then o = mask(qt@kt^T)@V + qt@S.  512 blocks.
__global__ __launch_bounds__(256) void k_chunk_out(
    const bf16* __restrict__ qt, const bf16* __restrict__ kt,
    const float* __restrict__ v, const float* __restrict__ U,
    const float* __restrict__ aL, float* __restrict__ y) {
  __shared__ float sQ[64 * 65];
  __shared__ float sKS[64 * 65];  // k-tilde (stride 65), later S (stride 64)
  __shared__ float sP[64 * 65];
  __shared__ float sV[64 * 64];
  int tid = threadIdx.x;
  int bhc = blockIdx.x;
  int c = bhc & 7, h = (bhc >> 3) & 31, b = bhc >> 8;
  size_t gbase = ((size_t)(b * Tz) + c * 64) * Cz + h * 64;
  size_t cbase = (size_t)bhc * 4096;

#pragma unroll
  for (int i = 0; i < 4; i++) {
    int i4 = tid + i * 256;
    int t = i4 >> 4, dq = i4 & 15;
    ushort4 qu = *(const ushort4*)&qt[cbase + i4 * 4];
    ushort4 ku = *(const ushort4*)&kt[cbase + i4 * 4];
    *(f32x4*)&sQ[t * 65 + dq * 4] = bf4_to_f32(qu);
    *(f32x4*)&sKS[t * 65 + dq * 4] = bf4_to_f32(ku);
  }
  __syncthreads();
  int tg = tid & 15, sg = tid >> 4;
  float p[4][4];
#pragma unroll
  for (int i = 0; i < 4; i++)
#pragma unroll
    for (int jx = 0; jx < 4; jx++) p[i][jx] = 0.f;
  for (int d = 0; d < 64; d++) {
    float qv[4], kv[4];
#pragma unroll
    for (int i = 0; i < 4; i++) qv[i] = sQ[(tg * 4 + i) * 65 + d];
#pragma unroll
    for (int jx = 0; jx < 4; jx++) kv[jx] = sKS[(sg * 4 + jx) * 65 + d];
#pragma unroll
    for (int i = 0; i < 4; i++)
#pragma unroll
      for (int jx = 0; jx < 4; jx++) p[i][jx] += qv[i] * kv[jx];
  }
#pragma unroll
  for (int i = 0; i < 4; i++) {
    int t = tg * 4 + i;
#pragma unroll
    for (int jx = 0; jx < 4; jx++) {
      int s = sg * 4 + jx;
      sP[t * 65 + s] = (s <= t) ? p[i][jx] : 0.f;
    }
  }
  // carry: S = sum_{j<c} U_j * prod of later aL (iterative), into registers
  f32x4 Sreg[4];
#pragma unroll
  for (int i = 0; i < 4; i++) Sreg[i] = (f32x4){0.f, 0.f, 0.f, 0.f};
  for (int j = 0; j < c; j++) {
    int bhj = bhc - c + j;
    size_t ub = (size_t)bhj * 4096;
#pragma unroll
    for (int i = 0; i < 4; i++) {
      int i4 = tid + i * 256;
      int d = i4 >> 4;
      float a = aL[(size_t)bhj * 64 + d];
      f32x4 u = *(const f32x4*)&U[ub + (size_t)i4 * 4];
      Sreg[i] = Sreg[i] * a + u;
    }
  }
  __syncthreads();  // everyone done reading sKS as k-tilde
#pragma unroll
  for (int i = 0; i < 4; i++) {
    int i4 = tid + i * 256;
    int t = i4 >> 4, dq = i4 & 15;
    *(f32x4*)&sKS[t * 64 + dq * 4] = Sreg[i];
    *(float4*)&sV[t * 64 + dq * 4] =
        *(const float4*)&v[gbase + (size_t)t * Cz + dq * 4];
  }
  __syncthreads();
  f32x4 o[4];
#pragma unroll
  for (int i = 0; i < 4; i++) o[i] = (f32x4){0.f, 0.f, 0.f, 0.f};
  for (int s = 0; s < 64; s++) {
    f32x4 vv = *(const f32x4*)&sV[s * 64 + sg * 4];
#pragma unroll
    for (int i = 0; i < 4; i++) {
      float pv = sP[(tg * 4 + i) * 65 + s];
      o[i] += pv * vv;
    }
  }
  for (int d = 0; d < 64; d++) {
    f32x4 sv = *(const f32x4*)&sKS[d * 64 + sg * 4];
#pragma unroll
    for (int i = 0; i < 4; i++) {
      float qv = sQ[(tg * 4 + i) * 65 + d];
      o[i] += qv * sv;
    }
  }
#pragma unroll
  for (int i = 0; i < 4; i++) {
    int t = tg * 4 + i;
    *(f32x4*)&y[gbase + (size_t)t * Cz + sg * 4] = o[i];
  }
}

// ---------------------------------------------------------------------------
// LayerNorm over C, write bf16
__global__ __launch_bounds__(256) void k_ln(
    const float* __restrict__ y, const float* __restrict__ lg,
    const float* __restrict__ lb, bf16* __restrict__ yb) {
  __shared__ float red[8];
  int t = blockIdx.x;
  int tid = threadIdx.x;
  const float4* y4 = (const float4*)(y + (size_t)t * Cz);
  float4 vals[2];
  float s = 0.f, s2 = 0.f;
#pragma unroll
  for (int u = 0; u < 2; u++) {
    float4 a = y4[tid + 256 * u];
    vals[u] = a;
    s += a.x + a.y + a.z + a.w;
    s2 += a.x * a.x + a.y * a.y + a.z * a.z + a.w * a.w;
  }
#pragma unroll
  for (int off = 32; off > 0; off >>= 1) {
    s += __shfl_down(s, off);
    s2 += __shfl_down(s2, off);
  }
  if ((tid & 63) == 0) {
    red[(tid >> 6) * 2] = s;
    red[(tid >> 6) * 2 + 1] = s2;
  }
  __syncthreads();
  float ts = red[0] + red[2] + red[4] + red[6];
  float ts2 = red[1] + red[3] + red[5] + red[7];
  float mu = ts / (float)Cz;
  float var = ts2 / (float)Cz - mu * mu;
  float inv = rsqrtf(var + 1e-5f);
  bf16* outp = yb + (size_t)t * Cz;
#pragma unroll
  for (int u = 0; u < 2; u++) {
    int c0 = (tid + 256 * u) * 4;
    float4 a = vals[u];
    outp[c0 + 0] = __float2bfloat16((a.x - mu) * inv * lg[c0 + 0] + lb[c0 + 0]);
    outp[c0 + 1] = __float2bfloat16((a.y - mu) * inv * lg[c0 + 1] + lb[c0 + 1]);
    outp[c0 + 2] = __float2bfloat16((a.z - mu) * inv * lg[c0 + 2] + lb[c0 + 2]);
    outp[c0 + 3] = __float2bfloat16((a.w - mu) * inv * lg[c0 + 3] + lb[c0 + 3]);
  }
}

// ---------------------------------------------------------------------------
extern "C" void kernel_launch(void* const* d_in, const int* in_sizes, int n_in,
                              void* d_out, int out_size, void* d_ws,
                              size_t ws_size, hipStream_t stream) {
  const float* x      = (const float*)d_in[0];
  const float* maa_x  = (const float*)d_in[1];
  const float* maa_r  = (const float*)d_in[2];
  const float* maa_k  = (const float*)d_in[3];
  const float* maa_v  = (const float*)d_in[4];
  const float* maa_w  = (const float*)d_in[5];
  const float* maa_w1 = (const float*)d_in[6];
  const float* maa_w2 = (const float*)d_in[7];
  const float* tdcay  = (const float*)d_in[8];
  const float* td_w1  = (const float*)d_in[9];
  const float* td_w2  = (const float*)d_in[10];
  const float* q_w    = (const float*)d_in[11];
  const float* q_b    = (const float*)d_in[12];
  const float* k_w    = (const float*)d_in[13];
  const float* k_b    = (const float*)d_in[14];
  const float* v_w    = (const float*)d_in[15];
  const float* v_b    = (const float*)d_in[16];
  const float* ln_g   = (const float*)d_in[17];
  const float* ln_b   = (const float*)d_in[18];
  const float* o_w    = (const float*)d_in[19];
  float* out = (float*)d_out;

  char* p = (char*)d_ws;
  auto alloc = [&](size_t bytes) {
    char* r = p;
    p += (bytes + 255) & ~(size_t)255;
    return r;
  };
  const size_t WB = (size_t)Cz * Cz * sizeof(bf16);    // 8 MB
  const size_t AF = (size_t)NTOK * Cz * sizeof(float); // 8 MB
  const size_t AB = (size_t)NTOK * Cz * sizeof(bf16);  // 4 MB

  bf16* qwt = (bf16*)alloc(WB);
  bf16* kwt = (bf16*)alloc(WB);
  bf16* vwt = (bf16*)alloc(WB);
  bf16* owt = (bf16*)alloc(WB);
  char* xslot = (char*)alloc(AF);     // xxxb/w1t/tdw1t -> qt/kt
  float* mm = (float*)alloc((size_t)NTOK * 128 * sizeof(float));  // -> aL
  bf16* xr = (bf16*)alloc(AB);
  bf16* xk = (bf16*)alloc(AB);
  bf16* xv = (bf16*)alloc(AB);
  char* xwslot = (char*)alloc(AF);    // xwb -> U
  float* tw = (float*)alloc((size_t)NTOK * 64 * sizeof(float));
  float* wlog = (float*)alloc(AF);
  char* scratch24 = (char*)alloc(3 * AF);  // mm_part/tw_part/qkv_part/y/o_part
  char* qkvf = (char*)alloc(3 * AF);       // dx (early) -> q,k,v f32
  bf16* yb = (bf16*)alloc(AB);

  bf16* xxxb = (bf16*)xslot;
  bf16* w1t = (bf16*)(xslot + 4 * 1024 * 1024);
  bf16* tdw1t = (bf16*)(xslot + 4 * 1024 * 1024 + 512 * 1024);
  bf16* qt = (bf16*)xslot;
  bf16* kt = (bf16*)(xslot + 4 * 1024 * 1024);
  bf16* xwb = (bf16*)xwslot;
  float* U = (float*)xwslot;
  float* aLbuf = mm;

  float* dx = (float*)qkvf;                      // dead after k_mproj
  float* q = (float*)qkvf;
  float* k = (float*)(qkvf + AF);
  float* v = (float*)(qkvf + 2 * AF);

  float* mm_part = (float*)scratch24;            // 16 MB, steps 2-3
  float* tw_part = (float*)(scratch24 + 2 * AF); // 8 MB, steps 5-6
  bf16* qkv_part = (bf16*)scratch24;             // 24 MB, steps 8-9
  float* y = (float*)scratch24;                  // 8 MB, steps 11-12
  bf16* o_part = (bf16*)scratch24;               // 16 MB, steps 13-14

  // 1. fused setup: weight transposes + token shift
  k_setup<<<18816, dim3(32, 8), 0, stream>>>(q_w, k_w, v_w, o_w, maa_w1, td_w1,
                                             x, maa_x, qwt, kwt, vwt, owt, w1t,
                                             tdw1t, dx, xxxb);
  // 2-3. mix LoRA stage 1
  k_lora_gemm<128><<<dim3(8, NSLICE), 256, 0, stream>>>(xxxb, w1t, mm_part);
  k_reduce_tanh<<<128, 256, 0, stream>>>(mm_part, mm, NTOK * 128 / 4);
  // 4. mix LoRA stage 2 + fused xr/xk/xv/xwb
  k_mproj<<<dim3(128, 8), 256, 0, stream>>>(mm, maa_w2, x, dx, maa_r, maa_k,
                                            maa_v, maa_w, xr, xk, xv, xwb);
  // 5-6. decay LoRA stage 1
  k_lora_gemm<64><<<dim3(8, NSLICE), 256, 0, stream>>>(xwb, tdw1t, tw_part);
  k_reduce_tanh<<<64, 256, 0, stream>>>(tw_part, tw, NTOK * 64 / 4);
  // 7. decay LoRA stage 2 -> wlog
  k_tdB<<<dim3(128, 8), 256, 0, stream>>>(tw, td_w2, tdcay, wlog);
  // 8-9. q,k,v projections: split-K=2 bf16 partials + combine(bias, q-scale)
  k_gemm_qkv_split<<<dim3(16, 8, 6), 256, 0, stream>>>(xr, xk, xv, qwt, kwt,
                                                       vwt, qkv_part);
  k_combine_qkv<<<2048, 256, 0, stream>>>(qkv_part, q_b, k_b, v_b, q, k, v);
  // 10. chunked GLA pass 1 (applies k-scale inline)
  k_chunk_prep<<<512, 256, 0, stream>>>(q, k, v, wlog, qt, kt, aLbuf, U);
  // 11. chunked GLA pass 2 (carry fused)
  k_chunk_out<<<512, 256, 0, stream>>>(qt, kt, v, U, aLbuf, y);
  // 12. LayerNorm -> bf16
  k_ln<<<NTOK, 256, 0, stream>>>(y, ln_g, ln_b, yb);
  // 13-14. output projection: split-K=4 bf16 partials + combine
  k_gemm_o_split<<<dim3(16, 8, 4), 256, 0, stream>>>(yb, owt, o_part);
  k_combine_o<<<2048, 256, 0, stream>>>(o_part, out);
}

// Round 7
// 292.499 us; speedup vs baseline: 2.0208x; 1.1161x over previous
//
#include <hip/hip_runtime.h>
#include <hip/hip_bf16.h>
#include <math.h>

// Problem constants
#define Bz 2
#define Tz 512
#define Cz 2048
#define Hh 32
#define DH 64
#define NTOK (Bz * Tz)   // 1024
#define NCH 8            // chunks per sequence (Tz/64)
#define NSLICE 32        // split-K slices for LoRA GEMMs (K-slice = 64)

typedef __hip_bfloat16 bf16;
typedef __attribute__((ext_vector_type(8))) short short8;
typedef __attribute__((ext_vector_type(4))) float f32x4;

// ---------------------------------------------------------------------------
__device__ __forceinline__ void load_lds16(const void* g, void* l) {
  __builtin_amdgcn_global_load_lds(
      (const __attribute__((address_space(1))) unsigned int*)g,
      (__attribute__((address_space(3))) unsigned int*)l,
      16, 0, 0);
}

__device__ __forceinline__ f32x4 bf4_to_f32(ushort4 u) {
  f32x4 r;
  r[0] = __builtin_bit_cast(float, (unsigned)u.x << 16);
  r[1] = __builtin_bit_cast(float, (unsigned)u.y << 16);
  r[2] = __builtin_bit_cast(float, (unsigned)u.z << 16);
  r[3] = __builtin_bit_cast(float, (unsigned)u.w << 16);
  return r;
}

// ---------------------------------------------------------------------------
// Shared MFMA GEMM core: A[M][K=2048] @ Bt[N][K]^T over k in [kBeg,kEnd).
// 4 waves arranged 2x2; wave tile (MT/2)x(NT/2); 16x16x32 bf16 MFMA.
template <int MT, int NT>
__device__ __forceinline__ void gemm_core(
    const bf16* __restrict__ A, const bf16* __restrict__ Bt,
    int M0, int N0, int kBeg, int kEnd,
    f32x4 (&acc)[MT / 32][NT / 32]) {
  constexpr int AI = MT / 32, BJ = NT / 32;
  constexpr int TSA = MT / 16, TS = (MT + NT) / 16;
  static_assert(TS % 4 == 0, "strips must divide among 4 waves");
  __shared__ alignas(16) bf16 As[MT * 32];
  __shared__ alignas(16) bf16 Bs[NT * 32];
  int tid = threadIdx.x, lane = tid & 63, wave = tid >> 6;
  int wm = wave & 1, wn = wave >> 1;
  int srow = lane >> 2, scol = (lane & 3) * 8;
  int fr = lane & 15, fk = (lane >> 4) * 8;
  const bf16* rA = As + (wm * (MT / 2) + fr) * 32 + fk;
  const bf16* rB = Bs + (wn * (NT / 2) + fr) * 32 + fk;

  for (int k0 = kBeg; k0 < kEnd; k0 += 32) {
#pragma unroll
    for (int s = wave; s < TS; s += 4) {
      if (s < TSA)
        load_lds16(A + (size_t)(M0 + s * 16 + srow) * Cz + k0 + scol,
                   As + s * 16 * 32);
      else
        load_lds16(Bt + (size_t)(N0 + (s - TSA) * 16 + srow) * Cz + k0 + scol,
                   Bs + (s - TSA) * 16 * 32);
    }
    __syncthreads();
    short8 af[AI], bf[BJ];
#pragma unroll
    for (int i = 0; i < AI; i++) af[i] = *(const short8*)(rA + i * 16 * 32);
#pragma unroll
    for (int j = 0; j < BJ; j++) bf[j] = *(const short8*)(rB + j * 16 * 32);
#pragma unroll
    for (int i = 0; i < AI; i++)
#pragma unroll
      for (int j = 0; j < BJ; j++)
        acc[i][j] = __builtin_amdgcn_mfma_f32_16x16x32_bf16(af[i], bf[j],
                                                            acc[i][j], 0, 0, 0);
    __syncthreads();
  }
}

// ---------------------------------------------------------------------------
// Fused setup. Block = (32,8). Ranges:
// [0,16384)       big weight transposes (4 x 64 x 64 tiles)
// [16384,16768)   w1/tdw1 transposes
// [16768,17024)   maa_w2 -> w2t [4][2048][32] bf16
// [17024,17152)   td_w2  -> tdw2t [2048][64] bf16
// [17152,19200)   token-shift prep
__global__ __launch_bounds__(256) void k_setup(
    const float* __restrict__ qw, const float* __restrict__ kw,
    const float* __restrict__ vw, const float* __restrict__ ow,
    const float* __restrict__ w1, const float* __restrict__ tdw1,
    const float* __restrict__ w2, const float* __restrict__ tdw2,
    const float* __restrict__ x, const float* __restrict__ maa_x,
    bf16* __restrict__ qwt, bf16* __restrict__ kwt, bf16* __restrict__ vwt,
    bf16* __restrict__ owt, bf16* __restrict__ w1t, bf16* __restrict__ tdw1t,
    bf16* __restrict__ w2t, bf16* __restrict__ tdw2t,
    float* __restrict__ dx, bf16* __restrict__ xxxb) {
  __shared__ float tile[32][33];
  int bid = blockIdx.x;
  int tx = threadIdx.x, ty = threadIdx.y;
  if (bid < 16384) {
    int w = bid >> 12, r = bid & 4095;
    const float* W = w == 0 ? qw : w == 1 ? kw : w == 2 ? vw : ow;
    bf16* O = w == 0 ? qwt : w == 1 ? kwt : w == 2 ? vwt : owt;
    int bx = (r & 63) * 32, by = (r >> 6) * 32;
#pragma unroll
    for (int i = 0; i < 4; i++)
      tile[ty + 8 * i][tx] = W[(size_t)(by + ty + 8 * i) * Cz + bx + tx];
    __syncthreads();
#pragma unroll
    for (int i = 0; i < 4; i++)
      O[(size_t)(bx + ty + 8 * i) * Cz + by + tx] =
          __float2bfloat16(tile[tx][ty + 8 * i]);
  } else if (bid < 16768) {
    int r = bid - 16384;
    int z = r >> 6;           // 0..5
    int bk = (r & 63) * 32;
    const float* W;
    bf16* O;
    int N, bn;
    if (z < 4) { W = w1; O = w1t; N = 128; bn = z * 32; }
    else       { W = tdw1; O = tdw1t; N = 64; bn = (z - 4) * 32; }
#pragma unroll
    for (int i = 0; i < 4; i++)
      tile[ty + 8 * i][tx] = W[(size_t)(bk + ty + 8 * i) * N + bn + tx];
    __syncthreads();
#pragma unroll
    for (int i = 0; i < 4; i++)
      O[(size_t)(bn + ty + 8 * i) * Cz + bk + tx] =
          __float2bfloat16(tile[tx][ty + 8 * i]);
  } else if (bid < 17024) {
    // maa_w2 [4*32][2048] -> w2t[r][c][d], d=0..31
    int r2 = bid - 16768;
    int rr = r2 >> 6, c0 = (r2 & 63) * 32;
#pragma unroll
    for (int i = 0; i < 4; i++)
      tile[ty + 8 * i][tx] = w2[(size_t)(rr * 32 + ty + 8 * i) * Cz + c0 + tx];
    __syncthreads();
#pragma unroll
    for (int i = 0; i < 4; i++)
      w2t[(size_t)(rr * 2048 + c0 + ty + 8 * i) * 32 + tx] =
          __float2bfloat16(tile[tx][ty + 8 * i]);
  } else if (bid < 17152) {
    // td_w2 [64][2048] -> tdw2t[c][k]
    int r2 = bid - 17024;
    int k0 = (r2 & 1) * 32, c0 = (r2 >> 1) * 32;
#pragma unroll
    for (int i = 0; i < 4; i++)
      tile[ty + 8 * i][tx] = tdw2[(size_t)(k0 + ty + 8 * i) * Cz + c0 + tx];
    __syncthreads();
#pragma unroll
    for (int i = 0; i < 4; i++)
      tdw2t[(size_t)(c0 + ty + 8 * i) * 64 + k0 + tx] =
          __float2bfloat16(tile[tx][ty + 8 * i]);
  } else {
    int r = bid - 17152;
    int tid = ty * 32 + tx;
    int i4 = r * 256 + tid;                 // over 262144 float4
    int row = i4 >> 9, t = row & (Tz - 1), c4 = i4 & 511;
    const float4* x4 = (const float4*)x;
    float4 xv = x4[i4];
    float4 xp = make_float4(0.f, 0.f, 0.f, 0.f);
    if (t != 0) xp = x4[i4 - 512];
    float4 mx = ((const float4*)maa_x)[c4];
    float4 d, xx;
    d.x = xp.x - xv.x; d.y = xp.y - xv.y; d.z = xp.z - xv.z; d.w = xp.w - xv.w;
    xx.x = xv.x + d.x * mx.x; xx.y = xv.y + d.y * mx.y;
    xx.z = xv.z + d.z * mx.z; xx.w = xv.w + d.w * mx.w;
    ((float4*)dx)[i4] = d;
    ushort4 u;
    u.x = __builtin_bit_cast(unsigned short, __float2bfloat16(xx.x));
    u.y = __builtin_bit_cast(unsigned short, __float2bfloat16(xx.y));
    u.z = __builtin_bit_cast(unsigned short, __float2bfloat16(xx.z));
    u.w = __builtin_bit_cast(unsigned short, __float2bfloat16(xx.w));
    ((ushort4*)xxxb)[i4] = u;
  }
}

// ---------------------------------------------------------------------------
// Split-K LoRA GEMM: part[slice][1024][NT] = A @ Bt^T over K-slice of 64.
template <int NT>
__global__ __launch_bounds__(256) void k_lora_gemm(
    const bf16* __restrict__ A, const bf16* __restrict__ Bt,
    float* __restrict__ part) {
  constexpr int KS = Cz / NSLICE;  // 64
  f32x4 acc[4][NT / 32];
#pragma unroll
  for (int i = 0; i < 4; i++)
#pragma unroll
    for (int j = 0; j < NT / 32; j++) acc[i][j] = (f32x4){0.f, 0.f, 0.f, 0.f};
  int bM = blockIdx.x, slice = blockIdx.y;
  gemm_core<128, NT>(A, Bt, bM * 128, 0, slice * KS, slice * KS + KS, acc);
  int lane = threadIdx.x & 63, wave = threadIdx.x >> 6;
  int wm = wave & 1, wn = wave >> 1;
  int r0 = (lane >> 4) * 4, cn = lane & 15;
#pragma unroll
  for (int i = 0; i < 4; i++) {
    int m = bM * 128 + wm * 64 + i * 16 + r0;
#pragma unroll
    for (int j = 0; j < NT / 32; j++) {
      int n = wn * (NT / 2) + j * 16 + cn;
#pragma unroll
      for (int r = 0; r < 4; r++)
        part[((size_t)slice * NTOK + m + r) * NT + n] = acc[i][j][r];
    }
  }
}

// ---------------------------------------------------------------------------
// out[i] = bf16(tanh(sum over NSLICE partials)).  One x4 per thread.
__global__ __launch_bounds__(256) void k_reduce_tanh(
    const float* __restrict__ part, bf16* __restrict__ out, int n4) {
  int i = blockIdx.x * 256 + threadIdx.x;
  f32x4 s = (f32x4){0.f, 0.f, 0.f, 0.f};
#pragma unroll 8
  for (int sl = 0; sl < NSLICE; sl++)
    s += *(const f32x4*)&part[(size_t)sl * n4 * 4 + i * 4];
  ushort4 u;
  u.x = __builtin_bit_cast(unsigned short, __float2bfloat16(tanhf(s[0])));
  u.y = __builtin_bit_cast(unsigned short, __float2bfloat16(tanhf(s[1])));
  u.z = __builtin_bit_cast(unsigned short, __float2bfloat16(tanhf(s[2])));
  u.w = __builtin_bit_cast(unsigned short, __float2bfloat16(tanhf(s[3])));
  ((ushort4*)out)[i] = u;
}

// ---------------------------------------------------------------------------
// MFMA mproj: m_r = mmb[1024x128](slice r) @ w2t[r][2048x32]^T, K=32.
// Fused epilogue: px = bf16(x + dx*(maa + m)).  grid (16, 8, 4).
__global__ __launch_bounds__(256) void k_mproj_mfma(
    const bf16* __restrict__ mmb, const bf16* __restrict__ w2t,
    const float* __restrict__ x, const float* __restrict__ dx,
    const float* __restrict__ maa_r, const float* __restrict__ maa_k,
    const float* __restrict__ maa_v, const float* __restrict__ maa_w,
    bf16* __restrict__ pxr, bf16* __restrict__ pxk,
    bf16* __restrict__ pxv, bf16* __restrict__ pxw) {
  __shared__ alignas(16) bf16 As[128 * 32];
  __shared__ alignas(16) bf16 Bs[128 * 32];
  int r = blockIdx.z;
  int n0 = blockIdx.x * 128, m0 = blockIdx.y * 128;
  int tid = threadIdx.x, lane = tid & 63, wave = tid >> 6;
  int wm = wave & 1, wn = wave >> 1;
  int srow = lane >> 2, scol = (lane & 3) * 8;
#pragma unroll
  for (int s = wave; s < 16; s += 4) {
    if (s < 8)
      load_lds16(mmb + (size_t)(m0 + s * 16 + srow) * 128 + r * 32 + scol,
                 As + s * 16 * 32);
    else
      load_lds16(w2t + ((size_t)r * 2048 + n0 + (s - 8) * 16 + srow) * 32 + scol,
                 Bs + (s - 8) * 16 * 32);
  }
  __syncthreads();
  int fr = lane & 15, fk = (lane >> 4) * 8;
  const bf16* rA = As + (wm * 64 + fr) * 32 + fk;
  const bf16* rB = Bs + (wn * 64 + fr) * 32 + fk;
  f32x4 acc[4][4];
  short8 af[4], bf[4];
#pragma unroll
  for (int i = 0; i < 4; i++) af[i] = *(const short8*)(rA + i * 16 * 32);
#pragma unroll
  for (int j = 0; j < 4; j++) bf[j] = *(const short8*)(rB + j * 16 * 32);
#pragma unroll
  for (int i = 0; i < 4; i++)
#pragma unroll
    for (int j = 0; j < 4; j++)
      acc[i][j] = __builtin_amdgcn_mfma_f32_16x16x32_bf16(
          af[i], bf[j], (f32x4){0.f, 0.f, 0.f, 0.f}, 0, 0, 0);
  const float* maa = r == 0 ? maa_r : r == 1 ? maa_k : r == 2 ? maa_v : maa_w;
  bf16* dst = r == 0 ? pxr : r == 1 ? pxk : r == 2 ? pxv : pxw;
  int r0 = (lane >> 4) * 4, cn = lane & 15;
#pragma unroll
  for (int i = 0; i < 4; i++) {
    int m = m0 + wm * 64 + i * 16 + r0;
#pragma unroll
    for (int j = 0; j < 4; j++) {
      int n = n0 + wn * 64 + j * 16 + cn;
      float ma = maa[n];
#pragma unroll
      for (int rr = 0; rr < 4; rr++) {
        size_t idx = (size_t)(m + rr) * Cz + n;
        dst[idx] = __float2bfloat16(x[idx] + dx[idx] * (ma + acc[i][j][rr]));
      }
    }
  }
}

// ---------------------------------------------------------------------------
// MFMA tdB: acc = twb[1024x64] @ tdw2t[2048x64]^T, K=64 (2 phases).
// Epilogue: wlog = max(-exp(td + acc), -5).  grid (16, 8).
__global__ __launch_bounds__(256) void k_tdB_mfma(
    const bf16* __restrict__ twb, const bf16* __restrict__ tdw2t,
    const float* __restrict__ td, float* __restrict__ wlog) {
  __shared__ alignas(16) bf16 As[128 * 32];
  __shared__ alignas(16) bf16 Bs[128 * 32];
  int n0 = blockIdx.x * 128, m0 = blockIdx.y * 128;
  int tid = threadIdx.x, lane = tid & 63, wave = tid >> 6;
  int wm = wave & 1, wn = wave >> 1;
  int srow = lane >> 2, scol = (lane & 3) * 8;
  int fr = lane & 15, fk = (lane >> 4) * 8;
  const bf16* rA = As + (wm * 64 + fr) * 32 + fk;
  const bf16* rB = Bs + (wn * 64 + fr) * 32 + fk;
  f32x4 acc[4][4];
#pragma unroll
  for (int i = 0; i < 4; i++)
#pragma unroll
    for (int j = 0; j < 4; j++) acc[i][j] = (f32x4){0.f, 0.f, 0.f, 0.f};
  for (int k0 = 0; k0 < 64; k0 += 32) {
#pragma unroll
    for (int s = wave; s < 16; s += 4) {
      if (s < 8)
        load_lds16(twb + (size_t)(m0 + s * 16 + srow) * 64 + k0 + scol,
                   As + s * 16 * 32);
      else
        load_lds16(tdw2t + (size_t)(n0 + (s - 8) * 16 + srow) * 64 + k0 + scol,
                   Bs + (s - 8) * 16 * 32);
    }
    __syncthreads();
    short8 af[4], bf[4];
#pragma unroll
    for (int i = 0; i < 4; i++) af[i] = *(const short8*)(rA + i * 16 * 32);
#pragma unroll
    for (int j = 0; j < 4; j++) bf[j] = *(const short8*)(rB + j * 16 * 32);
#pragma unroll
    for (int i = 0; i < 4; i++)
#pragma unroll
      for (int j = 0; j < 4; j++)
        acc[i][j] = __builtin_amdgcn_mfma_f32_16x16x32_bf16(af[i], bf[j],
                                                            acc[i][j], 0, 0, 0);
    __syncthreads();
  }
  int r0 = (lane >> 4) * 4, cn = lane & 15;
#pragma unroll
  for (int i = 0; i < 4; i++) {
    int m = m0 + wm * 64 + i * 16 + r0;
#pragma unroll
    for (int j = 0; j < 4; j++) {
      int n = n0 + wn * 64 + j * 16 + cn;
      float tdc = td[n];
#pragma unroll
      for (int rr = 0; rr < 4; rr++) {
        float wl = -expf(tdc + acc[i][j][rr]);
        wlog[(size_t)(m + rr) * Cz + n] = fmaxf(wl, -5.0f);
      }
    }
  }
}

// ---------------------------------------------------------------------------
// q/k/v projections, 128x128 tile, split-K=2, bf16 partials.
// grid (16 N-tiles, 8 M-tiles, 6 = proj*2+slice).
__global__ __launch_bounds__(256) void k_gemm_qkv_split(
    const bf16* __restrict__ xr, const bf16* __restrict__ xk,
    const bf16* __restrict__ xv, const bf16* __restrict__ qwt,
    const bf16* __restrict__ kwt, const bf16* __restrict__ vwt,
    bf16* __restrict__ part) {
  int z = blockIdx.z, proj = z >> 1, slice = z & 1;
  const bf16* A = proj == 0 ? xr : proj == 1 ? xk : xv;
  const bf16* W = proj == 0 ? qwt : proj == 1 ? kwt : vwt;
  f32x4 acc[4][4];
#pragma unroll
  for (int i = 0; i < 4; i++)
#pragma unroll
    for (int j = 0; j < 4; j++) acc[i][j] = (f32x4){0.f, 0.f, 0.f, 0.f};
  gemm_core<128, 128>(A, W, blockIdx.y * 128, blockIdx.x * 128, slice * 1024,
                      slice * 1024 + 1024, acc);
  int lane = threadIdx.x & 63, wave = threadIdx.x >> 6;
  int wm = wave & 1, wn = wave >> 1;
  int r0 = (lane >> 4) * 4, cn = lane & 15;
  bf16* dst = part + (size_t)z * NTOK * Cz;
#pragma unroll
  for (int i = 0; i < 4; i++) {
    int m = blockIdx.y * 128 + wm * 64 + i * 16 + r0;
#pragma unroll
    for (int j = 0; j < 4; j++) {
      int n = blockIdx.x * 128 + wn * 64 + j * 16 + cn;
#pragma unroll
      for (int r = 0; r < 4; r++)
        dst[(size_t)(m + r) * Cz + n] = __float2bfloat16(acc[i][j][r]);
    }
  }
}

// Combine qkv partials + bias (+ q scale). 2048 blocks.
__global__ __launch_bounds__(256) void k_combine_qkv(
    const bf16* __restrict__ part, const float* __restrict__ qb,
    const float* __restrict__ kb, const float* __restrict__ vb,
    float* __restrict__ q, float* __restrict__ k, float* __restrict__ v) {
  int i4 = blockIdx.x * 256 + threadIdx.x;
  int n4 = i4 & 511;
  const size_t P = (size_t)NTOK * Cz;
  const ushort4* pp = (const ushort4*)part;
  const size_t P4 = P / 4;
  float4 b;
  f32x4 s;
  s = bf4_to_f32(pp[i4]) + bf4_to_f32(pp[P4 + i4]);
  b = ((const float4*)qb)[n4];
  s = (s + (f32x4){b.x, b.y, b.z, b.w}) * 0.125f;
  *(f32x4*)&q[(size_t)i4 * 4] = s;
  s = bf4_to_f32(pp[2 * P4 + i4]) + bf4_to_f32(pp[3 * P4 + i4]);
  b = ((const float4*)kb)[n4];
  s = s + (f32x4){b.x, b.y, b.z, b.w};
  *(f32x4*)&k[(size_t)i4 * 4] = s;
  s = bf4_to_f32(pp[4 * P4 + i4]) + bf4_to_f32(pp[5 * P4 + i4]);
  b = ((const float4*)vb)[n4];
  s = s + (f32x4){b.x, b.y, b.z, b.w};
  *(f32x4*)&v[(size_t)i4 * 4] = s;
}

// ---------------------------------------------------------------------------
// Output projection, 128x128 tile, split-K=4, bf16 partials. grid (16,8,4).
__global__ __launch_bounds__(256) void k_gemm_o_split(
    const bf16* __restrict__ yb, const bf16* __restrict__ owt,
    bf16* __restrict__ part) {
  int z = blockIdx.z;
  f32x4 acc[4][4];
#pragma unroll
  for (int i = 0; i < 4; i++)
#pragma unroll
    for (int j = 0; j < 4; j++) acc[i][j] = (f32x4){0.f, 0.f, 0.f, 0.f};
  gemm_core<128, 128>(yb, owt, blockIdx.y * 128, blockIdx.x * 128, z * 512,
                      z * 512 + 512, acc);
  int lane = threadIdx.x & 63, wave = threadIdx.x >> 6;
  int wm = wave & 1, wn = wave >> 1;
  int r0 = (lane >> 4) * 4, cn = lane & 15;
  bf16* dst = part + (size_t)z * NTOK * Cz;
#pragma unroll
  for (int i = 0; i < 4; i++) {
    int m = blockIdx.y * 128 + wm * 64 + i * 16 + r0;
#pragma unroll
    for (int j = 0; j < 4; j++) {
      int n = blockIdx.x * 128 + wn * 64 + j * 16 + cn;
#pragma unroll
      for (int r = 0; r < 4; r++)
        dst[(size_t)(m + r) * Cz + n] = __float2bfloat16(acc[i][j][r]);
    }
  }
}

__global__ __launch_bounds__(256) void k_combine_o(
    const bf16* __restrict__ part, float* __restrict__ out) {
  int i4 = blockIdx.x * 256 + threadIdx.x;
  const size_t P4 = (size_t)NTOK * Cz / 4;
  const ushort4* pp = (const ushort4*)part;
  f32x4 s = bf4_to_f32(pp[i4]) + bf4_to_f32(pp[P4 + i4]) +
            bf4_to_f32(pp[2 * P4 + i4]) + bf4_to_f32(pp[3 * P4 + i4]);
  *(f32x4*)&out[(size_t)i4 * 4] = s;
}

// ---------------------------------------------------------------------------
// Chunked GLA pass 1: applies k-scale (1-exp(wlog)) inline; cumsum of wlog;
// emit qt=q*exp(cum), kt=ks*exp(-cum) (bf16), aL=exp(cumL), U = Kh^T V.
__global__ __launch_bounds__(256) void k_chunk_prep(
    const float* __restrict__ q, const float* __restrict__ k,
    const float* __restrict__ v, const float* __restrict__ wlog,
    bf16* __restrict__ qt, bf16* __restrict__ kt,
    float* __restrict__ aL, float* __restrict__ U) {
  __shared__ float sCum[64 * 64];
  __shared__ float sKh[64 * 64];
  __shared__ float sV[64 * 64];
  int tid = threadIdx.x;
  int bhc = blockIdx.x;
  int c = bhc & 7, h = (bhc >> 3) & 31, b = bhc >> 8;
  size_t gbase = ((size_t)(b * Tz) + c * 64) * Cz + h * 64;
  size_t cbase = (size_t)bhc * 4096;

#pragma unroll
  for (int i = 0; i < 4; i++) {
    int i4 = tid + i * 256;
    int t = i4 >> 4, dq = i4 & 15;
    size_t g = gbase + (size_t)t * Cz + dq * 4;
    *(float4*)&sCum[t * 64 + dq * 4] = *(const float4*)&wlog[g];
    *(float4*)&sKh[t * 64 + dq * 4] = *(const float4*)&k[g];
    *(float4*)&sV[t * 64 + dq * 4] = *(const float4*)&v[g];
  }
  __syncthreads();
#pragma unroll
  for (int i = 0; i < 16; i++) {
    int idx = tid + i * 256;
    sKh[idx] *= (1.f - expf(sCum[idx]));
  }
  __syncthreads();
  if (tid < 64) {
    float cum = 0.f;
#pragma unroll
    for (int t = 0; t < 64; t++) {
      cum += sCum[t * 64 + tid];
      sCum[t * 64 + tid] = cum;
    }
  }
  __syncthreads();
#pragma unroll
  for (int i = 0; i < 16; i++) {
    int idx = tid + i * 256;
    int t = idx >> 6, d = idx & 63;
    float cl = sCum[t * 64 + d];
    float cL = sCum[63 * 64 + d];
    float kraw = sKh[t * 64 + d];
    float qv = q[gbase + (size_t)t * Cz + d];
    float khv = kraw * expf(cL - cl);
    qt[cbase + idx] = __float2bfloat16(qv * expf(cl));
    kt[cbase + idx] = __float2bfloat16(kraw * expf(-cl));
    sKh[t * 64 + d] = khv;
    if (t == 63) aL[(size_t)bhc * 64 + d] = expf(cl);
  }
  __syncthreads();
  int j = tid & 63, dg = tid >> 6;
  float acc[16];
#pragma unroll
  for (int dd = 0; dd < 16; dd++) acc[dd] = 0.f;
  for (int s = 0; s < 64; s++) {
    float vs = sV[s * 64 + j];
#pragma unroll
    for (int dd = 0; dd < 16; dd++)
      acc[dd] += sKh[s * 64 + dg * 16 + dd] * vs;
  }
#pragma unroll
  for (int dd = 0; dd < 16; dd++)
    U[cbase + (size_t)(dg * 16 + dd) * 64 + j] = acc[dd];
}

// ---------------------------------------------------------------------------
// Chunked GLA pass 2 (carry fused): block (b,h,c) replays S = S*aL + U over
// chunks 0..c-1, then o = mask(qt@kt^T)@V + qt@S.  512 blocks.
__global__ __launch_bounds__(256) void k_chunk_out(
    const bf16* __restrict__ qt, const bf16* __restrict__ kt,
    const float* __restrict__ v, const float* __restrict__ U,
    const float* __restrict__ aL, float* __restrict__ y) {
  __shared__ float sQ[64 * 65];
  __shared__ float sKS[64 * 65];  // k-tilde (stride 65), later S (stride 64)
  __shared__ float sP[64 * 65];
  __shared__ float sV[64 * 64];
  int tid = threadIdx.x;
  int bhc = blockIdx.x;
  int c = bhc & 7, h = (bhc >> 3) & 31, b = bhc >> 8;
  size_t gbase = ((size_t)(b * Tz) + c * 64) * Cz + h * 64;
  size_t cbase = (size_t)bhc * 4096;

#pragma unroll
  for (int i = 0; i < 4; i++) {
    int i4 = tid + i * 256;
    int t = i4 >> 4, dq = i4 & 15;
    ushort4 qu = *(const ushort4*)&qt[cbase + i4 * 4];
    ushort4 ku = *(const ushort4*)&kt[cbase + i4 * 4];
    *(f32x4*)&sQ[t * 65 + dq * 4] = bf4_to_f32(qu);
    *(f32x4*)&sKS[t * 65 + dq * 4] = bf4_to_f32(ku);
  }
  __syncthreads();
  int tg = tid & 15, sg = tid >> 4;
  float p[4][4];
#pragma unroll
  for (int i = 0; i < 4; i++)
#pragma unroll
    for (int jx = 0; jx < 4; jx++) p[i][jx] = 0.f;
  for (int d = 0; d < 64; d++) {
    float qv[4], kv[4];
#pragma unroll
    for (int i = 0; i < 4; i++) qv[i] = sQ[(tg * 4 + i) * 65 + d];
#pragma unroll
    for (int jx = 0; jx < 4; jx++) kv[jx] = sKS[(sg * 4 + jx) * 65 + d];
#pragma unroll
    for (int i = 0; i < 4; i++)
#pragma unroll
      for (int jx = 0; jx < 4; jx++) p[i][jx] += qv[i] * kv[jx];
  }
#pragma unroll
  for (int i = 0; i < 4; i++) {
    int t = tg * 4 + i;
#pragma unroll
    for (int jx = 0; jx < 4; jx++) {
      int s = sg * 4 + jx;
      sP[t * 65 + s] = (s <= t) ? p[i][jx] : 0.f;
    }
  }
  f32x4 Sreg[4];
#pragma unroll
  for (int i = 0; i < 4; i++) Sreg[i] = (f32x4){0.f, 0.f, 0.f, 0.f};
  for (int j = 0; j < c; j++) {
    int bhj = bhc - c + j;
    size_t ub = (size_t)bhj * 4096;
#pragma unroll
    for (int i = 0; i < 4; i++) {
      int i4 = tid + i * 256;
      int d = i4 >> 4;
      float a = aL[(size_t)bhj * 64 + d];
      f32x4 u = *(const f32x4*)&U[ub + (size_t)i4 * 4];
      Sreg[i] = Sreg[i] * a + u;
    }
  }
  __syncthreads();  // everyone done reading sKS as k-tilde
#pragma unroll
  for (int i = 0; i < 4; i++) {
    int i4 = tid + i * 256;
    int t = i4 >> 4, dq = i4 & 15;
    *(f32x4*)&sKS[t * 64 + dq * 4] = Sreg[i];
    *(float4*)&sV[t * 64 + dq * 4] =
        *(const float4*)&v[gbase + (size_t)t * Cz + dq * 4];
  }
  __syncthreads();
  f32x4 o[4];
#pragma unroll
  for (int i = 0; i < 4; i++) o[i] = (f32x4){0.f, 0.f, 0.f, 0.f};
  for (int s = 0; s < 64; s++) {
    f32x4 vv = *(const f32x4*)&sV[s * 64 + sg * 4];
#pragma unroll
    for (int i = 0; i < 4; i++) {
      float pv = sP[(tg * 4 + i) * 65 + s];
      o[i] += pv * vv;
    }
  }
  for (int d = 0; d < 64; d++) {
    f32x4 sv = *(const f32x4*)&sKS[d * 64 + sg * 4];
#pragma unroll
    for (int i = 0; i < 4; i++) {
      float qv = sQ[(tg * 4 + i) * 65 + d];
      o[i] += qv * sv;
    }
  }
#pragma unroll
  for (int i = 0; i < 4; i++) {
    int t = tg * 4 + i;
    *(f32x4*)&y[gbase + (size_t)t * Cz + sg * 4] = o[i];
  }
}

// ---------------------------------------------------------------------------
// LayerNorm over C, write bf16
__global__ __launch_bounds__(256) void k_ln(
    const float* __restrict__ y, const float* __restrict__ lg,
    const float* __restrict__ lb, bf16* __restrict__ yb) {
  __shared__ float red[8];
  int t = blockIdx.x;
  int tid = threadIdx.x;
  const float4* y4 = (const float4*)(y + (size_t)t * Cz);
  float4 vals[2];
  float s = 0.f, s2 = 0.f;
#pragma unroll
  for (int u = 0; u < 2; u++) {
    float4 a = y4[tid + 256 * u];
    vals[u] = a;
    s += a.x + a.y + a.z + a.w;
    s2 += a.x * a.x + a.y * a.y + a.z * a.z + a.w * a.w;
  }
#pragma unroll
  for (int off = 32; off > 0; off >>= 1) {
    s += __shfl_down(s, off);
    s2 += __shfl_down(s2, off);
  }
  if ((tid & 63) == 0) {
    red[(tid >> 6) * 2] = s;
    red[(tid >> 6) * 2 + 1] = s2;
  }
  __syncthreads();
  float ts = red[0] + red[2] + red[4] + red[6];
  float ts2 = red[1] + red[3] + red[5] + red[7];
  float mu = ts / (float)Cz;
  float var = ts2 / (float)Cz - mu * mu;
  float inv = rsqrtf(var + 1e-5f);
  bf16* outp = yb + (size_t)t * Cz;
#pragma unroll
  for (int u = 0; u < 2; u++) {
    int c0 = (tid + 256 * u) * 4;
    float4 a = vals[u];
    outp[c0 + 0] = __float2bfloat16((a.x - mu) * inv * lg[c0 + 0] + lb[c0 + 0]);
    outp[c0 + 1] = __float2bfloat16((a.y - mu) * inv * lg[c0 + 1] + lb[c0 + 1]);
    outp[c0 + 2] = __float2bfloat16((a.z - mu) * inv * lg[c0 + 2] + lb[c0 + 2]);
    outp[c0 + 3] = __float2bfloat16((a.w - mu) * inv * lg[c0 + 3] + lb[c0 + 3]);
  }
}

// ---------------------------------------------------------------------------
extern "C" void kernel_launch(void* const* d_in, const int* in_sizes, int n_in,
                              void* d_out, int out_size, void* d_ws,
                              size_t ws_size, hipStream_t stream) {
  const float* x      = (const float*)d_in[0];
  const float* maa_x  = (const float*)d_in[1];
  const float* maa_r  = (const float*)d_in[2];
  const float* maa_k  = (const float*)d_in[3];
  const float* maa_v  = (const float*)d_in[4];
  const float* maa_w  = (const float*)d_in[5];
  const float* maa_w1 = (const float*)d_in[6];
  const float* maa_w2 = (const float*)d_in[7];
  const float* tdcay  = (const float*)d_in[8];
  const float* td_w1  = (const float*)d_in[9];
  const float* td_w2  = (const float*)d_in[10];
  const float* q_w    = (const float*)d_in[11];
  const float* q_b    = (const float*)d_in[12];
  const float* k_w    = (const float*)d_in[13];
  const float* k_b    = (const float*)d_in[14];
  const float* v_w    = (const float*)d_in[15];
  const float* v_b    = (const float*)d_in[16];
  const float* ln_g   = (const float*)d_in[17];
  const float* ln_b   = (const float*)d_in[18];
  const float* o_w    = (const float*)d_in[19];
  float* out = (float*)d_out;

  char* p = (char*)d_ws;
  auto alloc = [&](size_t bytes) {
    char* r = p;
    p += (bytes + 255) & ~(size_t)255;
    return r;
  };
  const size_t WB = (size_t)Cz * Cz * sizeof(bf16);    // 8 MB
  const size_t AF = (size_t)NTOK * Cz * sizeof(float); // 8 MB
  const size_t AB = (size_t)NTOK * Cz * sizeof(bf16);  // 4 MB

  bf16* qwt = (bf16*)alloc(WB);
  bf16* kwt = (bf16*)alloc(WB);
  bf16* vwt = (bf16*)alloc(WB);
  bf16* owt = (bf16*)alloc(WB);
  char* xslot = (char*)alloc(AF);     // xxxb/w1t/tdw1t/w2t/tdw2t -> qt/kt
  char* mmslot = (char*)alloc((size_t)NTOK * 128 * sizeof(float));  // mmb/aL
  bf16* xr = (bf16*)alloc(AB);
  bf16* xk = (bf16*)alloc(AB);
  bf16* xv = (bf16*)alloc(AB);
  char* xwslot = (char*)alloc(AF);    // xwb -> U
  bf16* twb = (bf16*)alloc((size_t)NTOK * 64 * sizeof(bf16));
  float* wlog = (float*)alloc(AF);
  char* scratch24 = (char*)alloc(3 * AF);  // mm_part/tw_part/qkv_part/y/o_part
  char* qkvf = (char*)alloc(3 * AF);       // dx (early) -> q,k,v f32
  bf16* yb = (bf16*)alloc(AB);

  bf16* xxxb = (bf16*)xslot;
  bf16* w1t = (bf16*)(xslot + 4 * 1024 * 1024);
  bf16* tdw1t = (bf16*)(xslot + 4 * 1024 * 1024 + 512 * 1024);
  bf16* w2t = (bf16*)(xslot + 4 * 1024 * 1024 + 768 * 1024);
  bf16* tdw2t = (bf16*)(xslot + 4 * 1024 * 1024 + 1280 * 1024);
  bf16* qt = (bf16*)xslot;
  bf16* kt = (bf16*)(xslot + 4 * 1024 * 1024);
  bf16* xwb = (bf16*)xwslot;
  float* U = (float*)xwslot;
  bf16* mmb = (bf16*)mmslot;
  float* aLbuf = (float*)(mmslot + 256 * 1024);  // 128 KB, disjoint from mmb

  float* dx = (float*)qkvf;                      // dead after k_mproj_mfma
  float* q = (float*)qkvf;
  float* k = (float*)(qkvf + AF);
  float* v = (float*)(qkvf + 2 * AF);

  float* mm_part = (float*)scratch24;            // 16 MB, steps 2-3
  float* tw_part = (float*)(scratch24 + 2 * AF); // 8 MB, steps 5-6
  bf16* qkv_part = (bf16*)scratch24;             // 24 MB, steps 8-9
  float* y = (float*)scratch24;                  // 8 MB, steps 11-12
  bf16* o_part = (bf16*)scratch24;               // 16 MB, steps 13-14

  // 1. fused setup: weight transposes + token shift
  k_setup<<<19200, dim3(32, 8), 0, stream>>>(
      q_w, k_w, v_w, o_w, maa_w1, td_w1, maa_w2, td_w2, x, maa_x, qwt, kwt,
      vwt, owt, w1t, tdw1t, w2t, tdw2t, dx, xxxb);
  // 2-3. mix LoRA stage 1
  k_lora_gemm<128><<<dim3(8, NSLICE), 256, 0, stream>>>(xxxb, w1t, mm_part);
  k_reduce_tanh<<<128, 256, 0, stream>>>(mm_part, mmb, NTOK * 128 / 4);
  // 4. mix LoRA stage 2 via MFMA, fused xr/xk/xv/xwb epilogue
  k_mproj_mfma<<<dim3(16, 8, 4), 256, 0, stream>>>(
      mmb, w2t, x, dx, maa_r, maa_k, maa_v, maa_w, xr, xk, xv, xwb);
  // 5-6. decay LoRA stage 1
  k_lora_gemm<64><<<dim3(8, NSLICE), 256, 0, stream>>>(xwb, tdw1t, tw_part);
  k_reduce_tanh<<<64, 256, 0, stream>>>(tw_part, twb, NTOK * 64 / 4);
  // 7. decay LoRA stage 2 via MFMA -> wlog
  k_tdB_mfma<<<dim3(16, 8), 256, 0, stream>>>(twb, tdw2t, tdcay, wlog);
  // 8-9. q,k,v projections: split-K=2 bf16 partials + combine(bias, q-scale)
  k_gemm_qkv_split<<<dim3(16, 8, 6), 256, 0, stream>>>(xr, xk, xv, qwt, kwt,
                                                       vwt, qkv_part);
  k_combine_qkv<<<2048, 256, 0, stream>>>(qkv_part, q_b, k_b, v_b, q, k, v);
  // 10. chunked GLA pass 1 (applies k-scale inline)
  k_chunk_prep<<<512, 256, 0, stream>>>(q, k, v, wlog, qt, kt, aLbuf, U);
  // 11. chunked GLA pass 2 (carry fused)
  k_chunk_out<<<512, 256, 0, stream>>>(qt, kt, v, U, aLbuf, y);
  // 12. LayerNorm -> bf16
  k_ln<<<NTOK, 256, 0, stream>>>(y, ln_g, ln_b, yb);
  // 13-14. output projection: split-K=4 bf16 partials + combine
  k_gemm_o_split<<<dim3(16, 8, 4), 256, 0, stream>>>(yb, owt, o_part);
  k_combine_o<<<2048, 256, 0, stream>>>(o_part, out);
}